// Round 1
// baseline (699.799 us; speedup 1.0000x reference)
//
#include <hip/hip_runtime.h>
#include <cstdint>
#include <math.h>

// MoE top-2 of 16 experts. N=131072, D=512, H=128, E=16, O=512.
// Pipeline (all on `stream`):
//   memset CTRL -> kconv (We->Wt bf16 [O][D], Wg1->hi/lo bf16 [H][D])
//   -> kgate (split-bf16 MFMA GEMM1 + fp32 GEMM2 + fp64 softmax/top2, margin-flag ambiguous)
//   -> krefine (fp64 exact gating for flagged tokens)
//   -> kcount/kscan/kscatter (bucket tokens by canonical expert pair)
//   -> kexpert (pair-bucket bf16 MFMA GEMM: one block computes BOTH experts of a
//      64-token x 128-col tile, single store, no atomics / no out memset)

#define NTOK 131072
#define DDIM 512
#define HID  128

typedef short  bf16x8 __attribute__((ext_vector_type(8)));
typedef float  f32x4  __attribute__((ext_vector_type(4)));

__device__ __forceinline__ ushort f2bf(float f){
  uint u = __float_as_uint(f);
  u += 0x7fffu + ((u >> 16) & 1u);        // RNE
  return (ushort)(u >> 16);
}
__device__ __forceinline__ float bf2f(ushort h){ return __uint_as_float(((uint)h) << 16); }

__device__ __forceinline__ void load_lds16(const void* g, void* l){
  __builtin_amdgcn_global_load_lds(
      (const __attribute__((address_space(1))) void*)(uintptr_t)g,
      (__attribute__((address_space(3))) void*)(uintptr_t)l, 16, 0, 0);
}

__device__ __forceinline__ f32x4 MFMA(bf16x8 a, bf16x8 b, f32x4 c){
  return __builtin_amdgcn_mfma_f32_16x16x32_bf16(a, b, c, 0, 0, 0);
}

// ---- LDS tile staging helpers -------------------------------------------------
// B tiles are staged with global_load_lds (linear LDS dest); the XOR bank-swizzle
// is applied by permuting the per-lane GLOBAL source (involution), reads apply
// the same XOR.  A tiles are reg-staged (fp32->bf16) with swizzled ds_write.

// [128 rows][32 cols] bf16 (8KB), global row pitch 512 bf16 (1024B). grow points at (row0, k0).
__device__ __forceinline__ void stageB32(const ushort* grow, char* lds, int tid){
  const char* gb = (const char*)grow;
  #pragma unroll
  for (int i = 0; i < 2; ++i){
    int lin = i*4096 + tid*16;
    int r = lin >> 6;
    int g = (lin >> 4) & 3;
    load_lds16(gb + r*1024 + ((g ^ (r & 3)) << 4), lds + i*4096 + ((tid >> 6) << 10));
  }
}
// [128 rows][64 cols] bf16 (16KB), pitch 512 bf16.
__device__ __forceinline__ void stageB64(const ushort* grow, char* lds, int tid){
  const char* gb = (const char*)grow;
  #pragma unroll
  for (int i = 0; i < 4; ++i){
    int lin = i*4096 + tid*16;
    int r = lin >> 7;
    int g = (lin >> 4) & 7;
    load_lds16(gb + r*1024 + ((g ^ (r & 7)) << 4), lds + i*4096 + ((tid >> 6) << 10));
  }
}
// read bf16x8 at logical (row r, k-chunk q[8 elems]) from a 64-col tile (pitch 128B)
__device__ __forceinline__ bf16x8 readF64(const char* buf, int r, int q){
  return *(const bf16x8*)(buf + r*128 + ((q ^ (r & 7)) << 4));
}
// same for 32-col tile (pitch 64B)
__device__ __forceinline__ bf16x8 readF32c(const char* buf, int r, int q){
  return *(const bf16x8*)(buf + r*64 + ((q ^ (r & 3)) << 4));
}

// A writers. 64-col tile: thread (ar=tid>>2 row, acq=tid&3 -> cols acq*16..+15)
__device__ __forceinline__ void writeA64(char* abuf, int ar, int acq, const float* fv, bool rv){
  uint pk[8];
  #pragma unroll
  for (int q=0;q<8;++q){
    ushort a0 = rv ? f2bf(fv[2*q])   : (ushort)0;
    ushort a1 = rv ? f2bf(fv[2*q+1]) : (ushort)0;
    pk[q] = (uint)a0 | ((uint)a1 << 16);
  }
  int g0 = (acq*2)   ^ (ar & 7);
  int g1 = (acq*2+1) ^ (ar & 7);
  *(uint4*)(abuf + ar*128 + (g0 << 4)) = make_uint4(pk[0],pk[1],pk[2],pk[3]);
  *(uint4*)(abuf + ar*128 + (g1 << 4)) = make_uint4(pk[4],pk[5],pk[6],pk[7]);
}
// 32-col tile, hi/lo split (gating): thread covers cols acq*8..+7
__device__ __forceinline__ void writeA2(char* hbuf, char* lbuf, int ar, int acq, const float* fv){
  uint ph[4], pl[4];
  #pragma unroll
  for (int q=0;q<4;++q){
    float f0 = fv[2*q], f1 = fv[2*q+1];
    ushort h0 = f2bf(f0), h1 = f2bf(f1);
    ushort s0 = f2bf(f0 - bf2f(h0)), s1 = f2bf(f1 - bf2f(h1));
    ph[q] = (uint)h0 | ((uint)h1 << 16);
    pl[q] = (uint)s0 | ((uint)s1 << 16);
  }
  int off = ar*64 + ((acq ^ (ar & 3)) << 4);
  *(uint4*)(hbuf + off) = make_uint4(ph[0],ph[1],ph[2],ph[3]);
  *(uint4*)(lbuf + off) = make_uint4(pl[0],pl[1],pl[2],pl[3]);
}

// ---- kconv: We [E][D][O] f32 -> Wt [E][O][D] bf16 ; Wg1 [D][H] f32 -> W1h/W1l [H][D] bf16
__global__ void kconv(const float* __restrict__ We, const float* __restrict__ Wg1,
                      ushort* __restrict__ Wt, ushort* __restrict__ W1h, ushort* __restrict__ W1l){
  __shared__ float sh[64*65];
  int bx = blockIdx.x, tid = threadIdx.x;
  if (bx < 1024){
    int e = bx >> 6, dt = (bx >> 3) & 7, ot = bx & 7;
    const float* src = We + (size_t)e*262144 + (size_t)dt*64*512 + ot*64;
    #pragma unroll
    for (int it=0; it<16; ++it){ int idx = it*256+tid; int dl = idx>>6, ol = idx&63;
      sh[dl*65+ol] = src[dl*512+ol]; }
    __syncthreads();
    ushort* dst = Wt + (size_t)e*262144 + (size_t)ot*64*512 + dt*64;
    #pragma unroll
    for (int it=0; it<16; ++it){ int idx = it*256+tid; int ol = idx>>6, dl = idx&63;
      dst[(size_t)ol*512+dl] = f2bf(sh[dl*65+ol]); }
  } else {
    int q = bx - 1024;            // 0..15
    int dt = q >> 1, ht = q & 1;  // 8 d-tiles x 2 h-tiles of 64
    const float* src = Wg1 + (size_t)dt*64*128 + ht*64;
    #pragma unroll
    for (int it=0; it<16; ++it){ int idx = it*256+tid; int dl = idx>>6, ol = idx&63;
      sh[dl*65+ol] = src[dl*128+ol]; }
    __syncthreads();
    #pragma unroll
    for (int it=0; it<16; ++it){ int idx = it*256+tid; int ol = idx>>6, dl = idx&63;
      float wv = sh[dl*65+ol];
      ushort hi = f2bf(wv);
      ushort lo = f2bf(wv - bf2f(hi));
      size_t o = (size_t)(ht*64+ol)*512 + dt*64+dl;
      W1h[o] = hi; W1l[o] = lo; }
  }
}

// ---- kgate: fused gating. Block = 64 tokens, 256 thr (4 waves, 2x2 wave grid, wave tile 32x64).
__global__ __launch_bounds__(256) void kgate(
    const float* __restrict__ x, const ushort* __restrict__ W1h, const ushort* __restrict__ W1l,
    const float* __restrict__ bg1, const float* __restrict__ Wg2, const float* __restrict__ bg2,
    int2* __restrict__ gate_e, float2* __restrict__ gate_g,
    int* __restrict__ refine_cnt, int* __restrict__ refine_list)
{
  __shared__ __align__(16) char sm[49152];
  const int BOFF = 16384;
  int tid = threadIdx.x, bid = blockIdx.x;
  int lane = tid & 63, w = tid >> 6, wm = w >> 1, wn = w & 1;
  int t0 = bid * 64;
  int ar = tid >> 2, acq = tid & 3;
  const float* xrow = x + (size_t)(t0 + ar) * DDIM;
  f32x4 acc[2][4];
  #pragma unroll
  for (int n=0;n<4;++n){
    float bb = bg1[wn*64 + n*16 + (lane & 15)];
    f32x4 z = {bb, bb, bb, bb};
    acc[0][n] = z; acc[1][n] = z;
  }
  // prologue: ks=0 -> buf0
  stageB32(W1h, sm + BOFF, tid);
  stageB32(W1l, sm + BOFF + 8192, tid);
  {
    float fv[8];
    *(float4*)&fv[0] = *(const float4*)(xrow + acq*8);
    *(float4*)&fv[4] = *(const float4*)(xrow + acq*8 + 4);
    writeA2(sm, sm + 4096, ar, acq, fv);
  }
  for (int ks = 0; ks < 16; ++ks){
    int b = ks & 1;
    asm volatile("s_waitcnt vmcnt(0)" ::: "memory");
    __syncthreads();
    float fv[8];
    if (ks < 15){
      int k2 = ks + 1, b2 = k2 & 1;
      stageB32(W1h + k2*32, sm + BOFF + b2*16384, tid);
      stageB32(W1l + k2*32, sm + BOFF + b2*16384 + 8192, tid);
      *(float4*)&fv[0] = *(const float4*)(xrow + k2*32 + acq*8);
      *(float4*)&fv[4] = *(const float4*)(xrow + k2*32 + acq*8 + 4);
    }
    const char* Ah = sm + b*8192;
    const char* Al = Ah + 4096;
    const char* Bh = sm + BOFF + b*16384;
    const char* Bl = Bh + 8192;
    bf16x8 ah[2], alv[2], bh[4], blv[4];
    #pragma unroll
    for (int m=0;m<2;++m){
      int r = wm*32 + m*16 + (lane & 15);
      ah[m]  = readF32c(Ah, r, lane >> 4);
      alv[m] = readF32c(Al, r, lane >> 4);
    }
    #pragma unroll
    for (int n=0;n<4;++n){
      int r = wn*64 + n*16 + (lane & 15);
      bh[n]  = readF32c(Bh, r, lane >> 4);
      blv[n] = readF32c(Bl, r, lane >> 4);
    }
    #pragma unroll
    for (int m=0;m<2;++m)
      #pragma unroll
      for (int n=0;n<4;++n){
        acc[m][n] = MFMA(ah[m],  bh[n],  acc[m][n]);   // hi*hi
        acc[m][n] = MFMA(ah[m],  blv[n], acc[m][n]);   // hi*lo
        acc[m][n] = MFMA(alv[m], bh[n],  acc[m][n]);   // lo*hi  (lo*lo dropped, ~2^-18)
      }
    if (ks < 15){
      int b2 = (ks + 1) & 1;
      writeA2(sm + b2*8192, sm + b2*8192 + 4096, ar, acq, fv);
    }
  }
  __syncthreads();
  // GELU (exact erf) -> h in LDS [64][132] f32 (padded pitch)
  float* hl = (float*)sm;
  #pragma unroll
  for (int m=0;m<2;++m)
    #pragma unroll
    for (int n=0;n<4;++n)
      #pragma unroll
      for (int j=0;j<4;++j){
        int row = wm*32 + m*16 + ((lane >> 4) << 2) + j;
        int col = wn*64 + n*16 + (lane & 15);
        float uv = acc[m][n][j];
        hl[row*132 + col] = 0.5f * uv * (1.0f + erff(uv * 0.70710678118654752f));
      }
  __syncthreads();
  // GEMM2: logits [64][16] f32. thread (tt=tid>>2 token, cc=tid&3 -> 4 experts)
  {
    int tt = tid >> 2, cc = tid & 3;
    float4 bb = *(const float4*)(bg2 + cc*4);
    float l0 = bb.x, l1 = bb.y, l2 = bb.z, l3 = bb.w;
    const float* hrow = hl + tt*132;
    #pragma unroll 8
    for (int i = 0; i < 128; ++i){
      float hv = hrow[i];
      float4 wv = *(const float4*)(Wg2 + i*16 + cc*4);
      l0 += hv*wv.x; l1 += hv*wv.y; l2 += hv*wv.z; l3 += hv*wv.w;
    }
    float* ll = (float*)(sm + 33792);
    *(float4*)(ll + tt*16 + cc*4) = make_float4(l0, l1, l2, l3);
  }
  __syncthreads();
  if (tid < 64){
    int t = t0 + tid;
    const float* l = (const float*)(sm + 33792) + tid*16;
    float b1 = -1e30f, b2 = -1e30f, b3 = -1e30f; int e1 = 0, e2 = 0;
    #pragma unroll
    for (int e = 0; e < 16; ++e){
      float v = l[e];
      if (v > b1){ b3 = b2; b2 = b1; e2 = e1; b1 = v; e1 = e; }
      else if (v > b2){ b3 = b2; b2 = v; e2 = e; }
      else if (v > b3){ b3 = v; }
    }
    double s = 0.0;
    #pragma unroll
    for (int e = 0; e < 16; ++e) s += exp((double)l[e] - (double)b1);
    double inv = 1.0 / s;
    gate_e[t] = make_int2(e1, e2);
    gate_g[t] = make_float2((float)(inv + 1e-4), (float)(exp((double)b2 - (double)b1) * inv + 1e-4));
    if (b2 - b3 < 2e-4f){            // ambiguous top2/top3 -> fp64 refine
      int pos = atomicAdd(refine_cnt, 1);
      refine_list[pos] = t;
    }
  }
}

// ---- krefine: exact fp64 gating for flagged tokens (one token per block, 128 thr)
__global__ __launch_bounds__(128) void krefine(
    const float* __restrict__ x, const float* __restrict__ Wg1, const float* __restrict__ bg1,
    const float* __restrict__ Wg2, const float* __restrict__ bg2,
    const int* __restrict__ refine_cnt, const int* __restrict__ refine_list,
    int2* __restrict__ gate_e, float2* __restrict__ gate_g)
{
  __shared__ float  xs[512];
  __shared__ double hd[128];
  __shared__ double ld[16];
  int tid = threadIdx.x;
  int rc = *refine_cnt;
  for (int i = blockIdx.x; i < rc; i += gridDim.x){
    __syncthreads();
    int t = refine_list[i];
    *(float4*)(xs + tid*4) = *(const float4*)(x + (size_t)t*DDIM + tid*4);
    __syncthreads();
    double a = (double)bg1[tid];
    for (int d = 0; d < 512; ++d) a += (double)xs[d] * (double)Wg1[d*128 + tid];
    hd[tid] = 0.5 * a * (1.0 + erf(a * 0.70710678118654752440));
    __syncthreads();
    if (tid < 16){
      double s = (double)bg2[tid];
      for (int k = 0; k < 128; ++k) s += hd[k] * (double)Wg2[k*16 + tid];
      ld[tid] = s;
    }
    __syncthreads();
    if (tid == 0){
      double b1 = -1e300, b2 = -1e300; int e1 = 0, e2 = 0;
      for (int e = 0; e < 16; ++e){
        double v = ld[e];
        if (v > b1){ b2 = b1; e2 = e1; b1 = v; e1 = e; }
        else if (v > b2){ b2 = v; e2 = e; }
      }
      double s = 0.0;
      for (int e = 0; e < 16; ++e) s += exp(ld[e] - b1);
      double inv = 1.0 / s;
      gate_e[t] = make_int2(e1, e2);
      gate_g[t] = make_float2((float)(inv + 1e-4), (float)(exp(b2 - b1) * inv + 1e-4));
    }
  }
}

// ---- pair-bucket build ----
__global__ void kcount(const int2* __restrict__ gate_e, int* __restrict__ counts){
  __shared__ int h[256];
  int tid = threadIdx.x;
  h[tid] = 0; __syncthreads();
  int t = blockIdx.x*256 + tid;
  int2 ee = gate_e[t];
  int a = min(ee.x, ee.y), b = max(ee.x, ee.y);
  atomicAdd(&h[a*16 + b], 1);
  __syncthreads();
  if (h[tid]) atomicAdd(&counts[tid], h[tid]);
}

__global__ void kscan(const int* __restrict__ counts, int* __restrict__ bases,
                      int* __restrict__ tile_pair, int* __restrict__ tile_row0, int* __restrict__ ntiles){
  if (threadIdx.x == 0 && blockIdx.x == 0){
    int tot = 0;
    for (int p = 0; p < 256; ++p){ bases[p] = tot; tot += counts[p]; }
    bases[256] = tot;
    int nt = 0;
    for (int p = 0; p < 256; ++p){
      int c = counts[p];
      for (int r = 0; r < c; r += 64){ tile_pair[nt] = p; tile_row0[nt] = r; ++nt; }
    }
    *ntiles = nt;
  }
}

__global__ void kscatter(const int2* __restrict__ gate_e, const float2* __restrict__ gate_g,
                         const int* __restrict__ bases, int* __restrict__ cursors,
                         int* __restrict__ pair_tok, float2* __restrict__ pair_g){
  __shared__ int h[256];
  __shared__ int gb[256];
  int tid = threadIdx.x;
  h[tid] = 0; __syncthreads();
  int t = blockIdx.x*256 + tid;
  int2 ee = gate_e[t]; float2 gg = gate_g[t];
  int a, b; float ga, gbv;
  if (ee.x < ee.y){ a = ee.x; b = ee.y; ga = gg.x; gbv = gg.y; }
  else            { a = ee.y; b = ee.x; ga = gg.y; gbv = gg.x; }
  int p = a*16 + b;
  int off = atomicAdd(&h[p], 1);
  __syncthreads();
  if (h[tid]) gb[tid] = bases[tid] + atomicAdd(&cursors[tid], h[tid]);
  __syncthreads();
  int slot = gb[p] + off;
  pair_tok[slot] = t;
  pair_g[slot] = make_float2(ga, gbv);
}

// ---- kexpert: pair-bucket GEMM. Block = (tile of 64 tokens) x (128-col slice of O).
// Loops both experts of the pair (16 K-steps of 64) and does a single store.
__global__ __launch_bounds__(256) void kexpert(
    const float* __restrict__ x, const ushort* __restrict__ Wt, const float* __restrict__ be,
    float* __restrict__ out,
    const int* __restrict__ counts, const int* __restrict__ bases,
    const int* __restrict__ tile_pair, const int* __restrict__ tile_row0, const int* __restrict__ ntiles,
    const int* __restrict__ pair_tok, const float2* __restrict__ pair_g)
{
  __shared__ __align__(16) char sm[49920];
  const int BOFF = 16384, LTOK = 49152, LGOFF = 49408;
  int tile = blockIdx.x >> 2, nt = blockIdx.x & 3;
  if (tile >= *ntiles) return;
  int p = tile_pair[tile], row0 = tile_row0[tile];
  int base = bases[p], cnt = counts[p];
  int eA = p >> 4, eB = p & 15;
  int tid = threadIdx.x, lane = tid & 63, w = tid >> 6;
  int wm = w >> 1, wn = w & 1;
  if (tid < 64){
    int rr = row0 + tid; bool v = rr < cnt;
    ((int*)(sm + LTOK))[tid] = v ? pair_tok[base + rr] : -1;
    ((float2*)(sm + LGOFF))[tid] = v ? pair_g[base + rr] : make_float2(0.f, 0.f);
  }
  int ar = tid >> 2, acq = tid & 3;
  int arr = row0 + ar;
  int tok_r = (arr < cnt) ? pair_tok[base + arr] : -1;
  bool rv = tok_r >= 0;
  const float* xrow = x + (size_t)(rv ? tok_r : 0) * DDIM;
  __syncthreads();
  const ushort* WA = Wt + (size_t)eA*262144 + (size_t)nt*128*512;
  const ushort* WB = Wt + (size_t)eB*262144 + (size_t)nt*128*512;
  // prologue: step 0 (expert A, ks=0) -> buf0
  stageB64(WA, sm + BOFF, tid);
  {
    float fv[16];
    #pragma unroll
    for (int q=0;q<4;++q) *(float4*)&fv[q*4] = *(const float4*)(xrow + acq*16 + q*4);
    writeA64(sm, ar, acq, fv, rv);
  }
  f32x4 acc[2][4], res[2][4];
  #pragma unroll
  for (int m=0;m<2;++m)
    #pragma unroll
    for (int n=0;n<4;++n) acc[m][n] = (f32x4){0.f,0.f,0.f,0.f};

  for (int u = 0; u < 16; ++u){
    int b = u & 1;
    asm volatile("s_waitcnt vmcnt(0)" ::: "memory");
    __syncthreads();
    float fv[16];
    int un = u + 1;
    if (un < 16){
      int ks2 = un & 7;
      const ushort* wsrc = ((un >> 3) ? WB : WA) + ks2*64;
      stageB64(wsrc, sm + BOFF + (un & 1)*16384, tid);
      #pragma unroll
      for (int q=0;q<4;++q)
        *(float4*)&fv[q*4] = *(const float4*)(xrow + ks2*64 + acq*16 + q*4);
    }
    const char* Ab = sm + b*8192;
    const char* Bb = sm + BOFF + b*16384;
    bf16x8 af[2][2], bfv[4][2];
    #pragma unroll
    for (int m=0;m<2;++m){
      int r = wm*32 + m*16 + (lane & 15);
      #pragma unroll
      for (int s2=0;s2<2;++s2) af[m][s2] = readF64(Ab, r, s2*4 + (lane >> 4));
    }
    #pragma unroll
    for (int n=0;n<4;++n){
      int r = wn*64 + n*16 + (lane & 15);
      #pragma unroll
      for (int s2=0;s2<2;++s2) bfv[n][s2] = readF64(Bb, r, s2*4 + (lane >> 4));
    }
    #pragma unroll
    for (int m=0;m<2;++m)
      #pragma unroll
      for (int n=0;n<4;++n){
        acc[m][n] = MFMA(af[m][0], bfv[n][0], acc[m][n]);
        acc[m][n] = MFMA(af[m][1], bfv[n][1], acc[m][n]);
      }
    if (un < 16) writeA64(sm + (un & 1)*8192, ar, acq, fv, rv);
    if ((u & 7) == 7){
      int ep = u >> 3;
      const float* bev = be + (size_t)(ep ? eB : eA)*DDIM + nt*128;
      float bcol[4];
      #pragma unroll
      for (int n=0;n<4;++n) bcol[n] = bev[wn*64 + n*16 + (lane & 15)];
      int tk[2][4]; float gvv[2][4];
      #pragma unroll
      for (int m=0;m<2;++m)
        #pragma unroll
        for (int j=0;j<4;++j){
          int row = wm*32 + m*16 + ((lane >> 4) << 2) + j;
          tk[m][j] = ((const int*)(sm + LTOK))[row];
          float2 g2 = ((const float2*)(sm + LGOFF))[row];
          gvv[m][j] = ep ? g2.y : g2.x;
        }
      if (ep == 0){
        #pragma unroll
        for (int m=0;m<2;++m)
          #pragma unroll
          for (int n=0;n<4;++n)
            #pragma unroll
            for (int j=0;j<4;++j)
              res[m][n][j] = gvv[m][j] * (acc[m][n][j] + bcol[n]);
        #pragma unroll
        for (int m=0;m<2;++m)
          #pragma unroll
          for (int n=0;n<4;++n) acc[m][n] = (f32x4){0.f,0.f,0.f,0.f};
      } else {
        #pragma unroll
        for (int m=0;m<2;++m)
          #pragma unroll
          for (int j=0;j<4;++j){
            if (tk[m][j] >= 0){
              float* orow = out + (size_t)tk[m][j]*DDIM + nt*128;
              #pragma unroll
              for (int n=0;n<4;++n){
                int col = wn*64 + n*16 + (lane & 15);
                orow[col] = res[m][n][j] + gvv[m][j] * (acc[m][n][j] + bcol[n]);
              }
            }
          }
      }
    }
  }
}

// ---- host launch --------------------------------------------------------------
extern "C" void kernel_launch(void* const* d_in, const int* in_sizes, int n_in,
                              void* d_out, int out_size, void* d_ws, size_t ws_size,
                              hipStream_t stream)
{
  const float* x   = (const float*)d_in[0];
  const float* Wg1 = (const float*)d_in[1];
  const float* bg1 = (const float*)d_in[2];
  const float* Wg2 = (const float*)d_in[3];
  const float* bg2 = (const float*)d_in[4];
  const float* We  = (const float*)d_in[5];
  const float* be  = (const float*)d_in[6];
  float* out = (float*)d_out;
  char* ws = (char*)d_ws;

  // ws layout (total ~12.3 MB)
  ushort* Wt        = (ushort*)(ws + 0);          // 8,388,608
  ushort* W1h       = (ushort*)(ws + 8388608);    //   131,072
  ushort* W1l       = (ushort*)(ws + 8519680);    //   131,072
  char*   CTRL      = ws + 8650752;               //     8,192
  int*  refine_cnt  = (int*)(CTRL);
  int*  ntiles      = (int*)(CTRL + 4);
  int*  counts      = (int*)(CTRL + 64);          // 256 ints
  int*  cursors     = (int*)(CTRL + 2048);        // 256 ints
  int*  bases       = (int*)(CTRL + 4096);        // 257 ints
  int2*   gate_e    = (int2*)(ws + 8658944);      // 1,048,576
  float2* gate_g    = (float2*)(ws + 9707520);    // 1,048,576
  int*  refine_list = (int*)(ws + 10756096);      //   524,288
  int*  pair_tok    = (int*)(ws + 11280384);      //   524,288
  float2* pair_g    = (float2*)(ws + 11804672);   // 1,048,576
  int*  tile_pair   = (int*)(ws + 12853248);      //    10,240
  int*  tile_row0   = (int*)(ws + 12863488);      //    10,240

  hipMemsetAsync(CTRL, 0, 8192, stream);
  hipLaunchKernelGGL(kconv,    dim3(1040),  dim3(256), 0, stream, We, Wg1, Wt, W1h, W1l);
  hipLaunchKernelGGL(kgate,    dim3(2048),  dim3(256), 0, stream, x, W1h, W1l, bg1, Wg2, bg2,
                     gate_e, gate_g, refine_cnt, refine_list);
  hipLaunchKernelGGL(krefine,  dim3(1024),  dim3(128), 0, stream, x, Wg1, bg1, Wg2, bg2,
                     refine_cnt, refine_list, gate_e, gate_g);
  hipLaunchKernelGGL(kcount,   dim3(512),   dim3(256), 0, stream, gate_e, counts);
  hipLaunchKernelGGL(kscan,    dim3(1),     dim3(64),  0, stream, counts, bases, tile_pair, tile_row0, ntiles);
  hipLaunchKernelGGL(kscatter, dim3(512),   dim3(256), 0, stream, gate_e, gate_g, bases, cursors, pair_tok, pair_g);
  hipLaunchKernelGGL(kexpert,  dim3(10240), dim3(256), 0, stream, x, Wt, be, out,
                     counts, bases, tile_pair, tile_row0, ntiles, pair_tok, pair_g);
  (void)in_sizes; (void)n_in; (void)out_size; (void)ws_size;
}

// Round 2
// 488.067 us; speedup vs baseline: 1.4338x; 1.4338x over previous
//
#include <hip/hip_runtime.h>
#include <cstdint>
#include <math.h>

// MoE top-2 of 16 experts. N=131072, D=512, H=128, E=16, O=512.
// Pipeline: memset CTRL -> kconv (We->Wt bf16 [O][D], Wg1->hi/lo bf16 [H][D])
//  -> kgate (split-bf16 MFMA gating + fp64 softmax/top2 + xbf16 store + pair histogram)
//  -> krefine (fp64 exact gating for ambiguous tokens; patches pair counts)
//  -> kscan (one-wave shuffle prefix scan + tile list) -> kscatter
//  -> kexpert (pair-bucket GEMM, 128 tok x 128 cols, both operands via
//     global_load_lds w/ pre-swizzled per-lane source; single store, no atomics)

#define NTOK 131072
#define DDIM 512

typedef short  bf16x8 __attribute__((ext_vector_type(8)));
typedef float  f32x4  __attribute__((ext_vector_type(4)));

__device__ __forceinline__ ushort f2bf(float f){
  uint u = __float_as_uint(f);
  u += 0x7fffu + ((u >> 16) & 1u);        // RNE
  return (ushort)(u >> 16);
}
__device__ __forceinline__ float bf2f(ushort h){ return __uint_as_float(((uint)h) << 16); }

__device__ __forceinline__ void load_lds16(const void* g, void* l){
  __builtin_amdgcn_global_load_lds(
      (const __attribute__((address_space(1))) void*)(uintptr_t)g,
      (__attribute__((address_space(3))) void*)(uintptr_t)l, 16, 0, 0);
}

__device__ __forceinline__ f32x4 MFMA(bf16x8 a, bf16x8 b, f32x4 c){
  return __builtin_amdgcn_mfma_f32_16x16x32_bf16(a, b, c, 0, 0, 0);
}

// ---- swizzled LDS helpers -----------------------------------------------------
// 64-col bf16 tile (pitch 128B): logical (row r, 16B chunk q) lives at byte
// r*128 + ((q ^ (r&7))<<4).  Stagers place data accordingly (source pre-swizzle).
__device__ __forceinline__ bf16x8 readF64(const char* buf, int r, int q){
  return *(const bf16x8*)(buf + r*128 + ((q ^ (r & 7)) << 4));
}
// 32-col bf16 tile (pitch 64B)
__device__ __forceinline__ bf16x8 readF32c(const char* buf, int r, int q){
  return *(const bf16x8*)(buf + r*64 + ((q ^ (r & 3)) << 4));
}

// stage [128 rows][32 cols] bf16 (8KB) via global_load_lds; global pitch 1024B.
__device__ __forceinline__ void stageB32(const ushort* grow, char* lds, int tid){
  const char* gb = (const char*)grow;
  #pragma unroll
  for (int i = 0; i < 2; ++i){
    int lin = i*4096 + tid*16;
    int r = lin >> 6;
    int g = (lin >> 4) & 3;
    load_lds16(gb + r*1024 + ((g ^ (r & 3)) << 4), lds + i*4096 + ((tid >> 6) << 10));
  }
}

// pack 8 fp32 -> hi/lo bf16 pairs
__device__ __forceinline__ void pack8(const float* fv, uint* ph, uint* pl){
  #pragma unroll
  for (int q=0;q<4;++q){
    float f0 = fv[2*q], f1 = fv[2*q+1];
    ushort h0 = f2bf(f0), h1 = f2bf(f1);
    ushort s0 = f2bf(f0 - bf2f(h0)), s1 = f2bf(f1 - bf2f(h1));
    ph[q] = (uint)h0 | ((uint)h1 << 16);
    pl[q] = (uint)s0 | ((uint)s1 << 16);
  }
}
__device__ __forceinline__ void writeA2p(char* hbuf, char* lbuf, int ar, int acq,
                                         const uint* ph, const uint* pl){
  int off = ar*64 + ((acq ^ (ar & 3)) << 4);
  *(uint4*)(hbuf + off) = make_uint4(ph[0],ph[1],ph[2],ph[3]);
  *(uint4*)(lbuf + off) = make_uint4(pl[0],pl[1],pl[2],pl[3]);
}

// ---- kconv: We [E][D][O] f32 -> Wt [E][O][D] bf16 ; Wg1 [D][H] f32 -> W1h/W1l [H][D] bf16
__global__ void kconv(const float* __restrict__ We, const float* __restrict__ Wg1,
                      ushort* __restrict__ Wt, ushort* __restrict__ W1h, ushort* __restrict__ W1l){
  __shared__ float sh[64*65];
  int bx = blockIdx.x, tid = threadIdx.x;
  if (bx < 1024){
    int e = bx >> 6, dt = (bx >> 3) & 7, ot = bx & 7;
    const float* src = We + (size_t)e*262144 + (size_t)dt*64*512 + ot*64;
    #pragma unroll
    for (int it=0; it<16; ++it){ int idx = it*256+tid; int dl = idx>>6, ol = idx&63;
      sh[dl*65+ol] = src[dl*512+ol]; }
    __syncthreads();
    ushort* dst = Wt + (size_t)e*262144 + (size_t)ot*64*512 + dt*64;
    #pragma unroll
    for (int it=0; it<16; ++it){ int idx = it*256+tid; int ol = idx>>6, dl = idx&63;
      dst[(size_t)ol*512+dl] = f2bf(sh[dl*65+ol]); }
  } else {
    int q = bx - 1024;
    int dt = q >> 1, ht = q & 1;
    const float* src = Wg1 + (size_t)dt*64*128 + ht*64;
    #pragma unroll
    for (int it=0; it<16; ++it){ int idx = it*256+tid; int dl = idx>>6, ol = idx&63;
      sh[dl*65+ol] = src[dl*128+ol]; }
    __syncthreads();
    #pragma unroll
    for (int it=0; it<16; ++it){ int idx = it*256+tid; int ol = idx>>6, dl = idx&63;
      float wv = sh[dl*65+ol];
      ushort hi = f2bf(wv);
      ushort lo = f2bf(wv - bf2f(hi));
      size_t o = (size_t)(ht*64+ol)*512 + dt*64+dl;
      W1h[o] = hi; W1l[o] = lo; }
  }
}

// ---- kgate: fused gating + xbf16 producer + pair histogram.
__global__ __launch_bounds__(256) void kgate(
    const float* __restrict__ x, const ushort* __restrict__ W1h, const ushort* __restrict__ W1l,
    const float* __restrict__ bg1, const float* __restrict__ Wg2, const float* __restrict__ bg2,
    ushort* __restrict__ xbf,
    int2* __restrict__ gate_e, float2* __restrict__ gate_g,
    int* __restrict__ refine_cnt, int* __restrict__ refine_list, int* __restrict__ counts)
{
  __shared__ __align__(16) char sm[49152];
  const int BOFF = 16384;
  int tid = threadIdx.x, bid = blockIdx.x;
  int lane = tid & 63, w = tid >> 6, wm = w >> 1, wn = w & 1;
  int t0 = bid * 64;
  int ar = tid >> 2, acq = tid & 3;
  const float* xrow = x + (size_t)(t0 + ar) * DDIM;
  char* xbfb = (char*)xbf;
  f32x4 acc[2][4];
  #pragma unroll
  for (int n=0;n<4;++n){
    float bb = bg1[wn*64 + n*16 + (lane & 15)];
    f32x4 z = {bb, bb, bb, bb};
    acc[0][n] = z; acc[1][n] = z;
  }
  stageB32(W1h, sm + BOFF, tid);
  stageB32(W1l, sm + BOFF + 8192, tid);
  {
    float fv[8];
    *(float4*)&fv[0] = *(const float4*)(xrow + acq*8);
    *(float4*)&fv[4] = *(const float4*)(xrow + acq*8 + 4);
    uint ph[4], pl[4];
    pack8(fv, ph, pl);
    if (xbf) *(uint4*)(xbfb + (size_t)(t0+ar)*1024 + acq*16) = make_uint4(ph[0],ph[1],ph[2],ph[3]);
    writeA2p(sm, sm + 4096, ar, acq, ph, pl);
  }
  for (int ks = 0; ks < 16; ++ks){
    int b = ks & 1;
    asm volatile("s_waitcnt vmcnt(0)" ::: "memory");
    __syncthreads();
    uint ph[4], pl[4];
    if (ks < 15){
      int k2 = ks + 1, b2 = k2 & 1;
      stageB32(W1h + k2*32, sm + BOFF + b2*16384, tid);
      stageB32(W1l + k2*32, sm + BOFF + b2*16384 + 8192, tid);
      float fv[8];
      *(float4*)&fv[0] = *(const float4*)(xrow + k2*32 + acq*8);
      *(float4*)&fv[4] = *(const float4*)(xrow + k2*32 + acq*8 + 4);
      pack8(fv, ph, pl);
      if (xbf) *(uint4*)(xbfb + (size_t)(t0+ar)*1024 + k2*64 + acq*16) = make_uint4(ph[0],ph[1],ph[2],ph[3]);
    }
    const char* Ah = sm + b*8192;
    const char* Al = Ah + 4096;
    const char* Bh = sm + BOFF + b*16384;
    const char* Bl = Bh + 8192;
    bf16x8 ah[2], alv[2], bh[4], blv[4];
    #pragma unroll
    for (int m=0;m<2;++m){
      int r = wm*32 + m*16 + (lane & 15);
      ah[m]  = readF32c(Ah, r, lane >> 4);
      alv[m] = readF32c(Al, r, lane >> 4);
    }
    #pragma unroll
    for (int n=0;n<4;++n){
      int r = wn*64 + n*16 + (lane & 15);
      bh[n]  = readF32c(Bh, r, lane >> 4);
      blv[n] = readF32c(Bl, r, lane >> 4);
    }
    #pragma unroll
    for (int m=0;m<2;++m)
      #pragma unroll
      for (int n=0;n<4;++n){
        acc[m][n] = MFMA(ah[m],  bh[n],  acc[m][n]);
        acc[m][n] = MFMA(ah[m],  blv[n], acc[m][n]);
        acc[m][n] = MFMA(alv[m], bh[n],  acc[m][n]);
      }
    if (ks < 15){
      int b2 = (ks + 1) & 1;
      writeA2p(sm + b2*8192, sm + b2*8192 + 4096, ar, acq, ph, pl);
    }
  }
  __syncthreads();
  float* hl = (float*)sm;
  #pragma unroll
  for (int m=0;m<2;++m)
    #pragma unroll
    for (int n=0;n<4;++n)
      #pragma unroll
      for (int j=0;j<4;++j){
        int row = wm*32 + m*16 + ((lane >> 4) << 2) + j;
        int col = wn*64 + n*16 + (lane & 15);
        float uv = acc[m][n][j];
        hl[row*132 + col] = 0.5f * uv * (1.0f + erff(uv * 0.70710678118654752f));
      }
  __syncthreads();
  {
    int tt = tid >> 2, cc = tid & 3;
    float4 bb = *(const float4*)(bg2 + cc*4);
    float l0 = bb.x, l1 = bb.y, l2 = bb.z, l3 = bb.w;
    const float* hrow = hl + tt*132;
    #pragma unroll 8
    for (int i = 0; i < 128; ++i){
      float hv = hrow[i];
      float4 wv = *(const float4*)(Wg2 + i*16 + cc*4);
      l0 += hv*wv.x; l1 += hv*wv.y; l2 += hv*wv.z; l3 += hv*wv.w;
    }
    float* ll = (float*)(sm + 33792);
    *(float4*)(ll + tt*16 + cc*4) = make_float4(l0, l1, l2, l3);
  }
  int* hist = (int*)(sm + 40960);
  hist[tid] = 0;
  __syncthreads();
  if (tid < 64){
    int t = t0 + tid;
    const float* l = (const float*)(sm + 33792) + tid*16;
    float b1 = -1e30f, b2 = -1e30f, b3 = -1e30f; int e1 = 0, e2 = 0;
    #pragma unroll
    for (int e = 0; e < 16; ++e){
      float v = l[e];
      if (v > b1){ b3 = b2; b2 = b1; e2 = e1; b1 = v; e1 = e; }
      else if (v > b2){ b3 = b2; b2 = v; e2 = e; }
      else if (v > b3){ b3 = v; }
    }
    double s = 0.0;
    #pragma unroll
    for (int e = 0; e < 16; ++e) s += exp((double)l[e] - (double)b1);
    double inv = 1.0 / s;
    gate_e[t] = make_int2(e1, e2);
    gate_g[t] = make_float2((float)(inv + 1e-4), (float)(exp((double)b2 - (double)b1) * inv + 1e-4));
    if (b2 - b3 < 2e-4f){
      int pos = atomicAdd(refine_cnt, 1);
      refine_list[pos] = t;
    }
    int pa = min(e1, e2), pb = max(e1, e2);
    atomicAdd(&hist[pa*16 + pb], 1);
  }
  __syncthreads();
  if (hist[tid]) atomicAdd(&counts[tid], hist[tid]);
}

// ---- krefine: exact fp64 gating for flagged tokens; patches pair counts.
__global__ __launch_bounds__(128) void krefine(
    const float* __restrict__ x, const float* __restrict__ Wg1, const float* __restrict__ bg1,
    const float* __restrict__ Wg2, const float* __restrict__ bg2,
    const int* __restrict__ refine_cnt, const int* __restrict__ refine_list,
    int2* __restrict__ gate_e, float2* __restrict__ gate_g, int* __restrict__ counts)
{
  __shared__ float  xs[512];
  __shared__ double hd[128];
  __shared__ double ld[16];
  int tid = threadIdx.x;
  int rc = *refine_cnt;
  for (int i = blockIdx.x; i < rc; i += gridDim.x){
    __syncthreads();
    int t = refine_list[i];
    *(float4*)(xs + tid*4) = *(const float4*)(x + (size_t)t*DDIM + tid*4);
    __syncthreads();
    double a = (double)bg1[tid];
    for (int d = 0; d < 512; ++d) a += (double)xs[d] * (double)Wg1[d*128 + tid];
    hd[tid] = 0.5 * a * (1.0 + erf(a * 0.70710678118654752440));
    __syncthreads();
    if (tid < 16){
      double s = (double)bg2[tid];
      for (int k = 0; k < 128; ++k) s += hd[k] * (double)Wg2[k*16 + tid];
      ld[tid] = s;
    }
    __syncthreads();
    if (tid == 0){
      int2 olde = gate_e[t];
      double b1 = -1e300, b2 = -1e300; int e1 = 0, e2 = 0;
      for (int e = 0; e < 16; ++e){
        double v = ld[e];
        if (v > b1){ b2 = b1; e2 = e1; b1 = v; e1 = e; }
        else if (v > b2){ b2 = v; e2 = e; }
      }
      double s = 0.0;
      for (int e = 0; e < 16; ++e) s += exp(ld[e] - b1);
      double inv = 1.0 / s;
      int oldp = min(olde.x, olde.y)*16 + max(olde.x, olde.y);
      int newp = min(e1, e2)*16 + max(e1, e2);
      if (oldp != newp){ atomicSub(&counts[oldp], 1); atomicAdd(&counts[newp], 1); }
      gate_e[t] = make_int2(e1, e2);
      gate_g[t] = make_float2((float)(inv + 1e-4), (float)(exp(b2 - b1) * inv + 1e-4));
    }
  }
}

// ---- kscan: one wave. prefix over 256 pair counts + 128-row tile list.
__global__ void kscan(const int* __restrict__ counts, int* __restrict__ bases,
                      int* __restrict__ tile_pair, int* __restrict__ tile_row0, int* __restrict__ ntiles){
  int l = threadIdx.x;
  int4 c = *(const int4*)(counts + l*4);
  int s = c.x + c.y + c.z + c.w;
  int ps = s;
  #pragma unroll
  for (int d = 1; d < 64; d <<= 1){ int v = __shfl_up(ps, d); if (l >= d) ps += v; }
  int ex = ps - s;
  bases[4*l+0] = ex;
  bases[4*l+1] = ex + c.x;
  bases[4*l+2] = ex + c.x + c.y;
  bases[4*l+3] = ex + c.x + c.y + c.z;
  if (l == 63) bases[256] = ex + s;
  int t0 = (c.x + 127) >> 7, t1 = (c.y + 127) >> 7, t2 = (c.z + 127) >> 7, t3 = (c.w + 127) >> 7;
  int ts = t0 + t1 + t2 + t3;
  int pt = ts;
  #pragma unroll
  for (int d = 1; d < 64; d <<= 1){ int v = __shfl_up(pt, d); if (l >= d) pt += v; }
  int ext = pt - ts;
  if (l == 63) *ntiles = ext + ts;
  int tb = ext;
  int cc[4] = {c.x, c.y, c.z, c.w};
  #pragma unroll
  for (int j = 0; j < 4; ++j){
    int pp = 4*l + j;
    for (int r = 0; r < cc[j]; r += 128){ tile_pair[tb] = pp; tile_row0[tb] = r; ++tb; }
  }
}

__global__ void kscatter(const int2* __restrict__ gate_e, const float2* __restrict__ gate_g,
                         const int* __restrict__ bases, int* __restrict__ cursors,
                         int* __restrict__ pair_tok, float2* __restrict__ pair_g){
  __shared__ int h[256];
  __shared__ int gb[256];
  int tid = threadIdx.x;
  h[tid] = 0; __syncthreads();
  int t = blockIdx.x*256 + tid;
  int2 ee = gate_e[t]; float2 gg = gate_g[t];
  int a, b; float ga, gbv;
  if (ee.x < ee.y){ a = ee.x; b = ee.y; ga = gg.x; gbv = gg.y; }
  else            { a = ee.y; b = ee.x; ga = gg.y; gbv = gg.x; }
  int p = a*16 + b;
  int off = atomicAdd(&h[p], 1);
  __syncthreads();
  if (h[tid]) gb[tid] = bases[tid] + atomicAdd(&cursors[tid], h[tid]);
  __syncthreads();
  int slot = gb[p] + off;
  pair_tok[slot] = t;
  pair_g[slot] = make_float2(ga, gbv);
}

// ---- kexpert: pair-bucket GEMM. Block = 128 tokens x 128 out-cols, both experts.
// BF16A=1: A gathered from xbf via global_load_lds (per-lane source addr).
// BF16A=0: A reg-staged from fp32 x (fallback when ws lacks room for xbf).
template<int BF16A>
__global__ __launch_bounds__(256, 2) void kexpert(
    const float* __restrict__ x, const ushort* __restrict__ xbf,
    const ushort* __restrict__ Wt, const float* __restrict__ be,
    float* __restrict__ out,
    const int* __restrict__ counts, const int* __restrict__ bases,
    const int* __restrict__ tile_pair, const int* __restrict__ tile_row0, const int* __restrict__ ntiles,
    const int* __restrict__ pair_tok, const float2* __restrict__ pair_g)
{
  __shared__ __align__(16) char sm[67072];
  const int ABUF = 0, BBUF = 32768, LTOK = 65536, LGOFF = 66048;
  int tile = blockIdx.x >> 2, nt = blockIdx.x & 3;
  if (tile >= *ntiles) return;
  int p = tile_pair[tile], row0 = tile_row0[tile];
  int base = bases[p], cnt = counts[p];
  int eA = p >> 4, eB = p & 15;
  int tid = threadIdx.x, lane = tid & 63;
  int w = tid >> 6, wm = w >> 1, wn = w & 1;
  if (tid < 128){
    int rr = row0 + tid; bool v = rr < cnt;
    ((int*)(sm + LTOK))[tid] = v ? pair_tok[base + rr] : -1;
    ((float2*)(sm + LGOFF))[tid] = v ? pair_g[base + rr] : make_float2(0.f, 0.f);
  }
  __syncthreads();

  // B staging bases (4 issues/thread, 16KB tile, rows = out-cols)
  const char* wb = (const char*)Wt;
  int grp = tid >> 3;                    // row within a 32-row issue group
  int gch = tid & 7;                     // 16B chunk
  int sw  = (gch ^ (grp & 7)) << 4;      // (rows are i*32+grp, so row&7 == grp&7)
  long long edelt = ((long long)eB - (long long)eA) * 524288;
  const char* srcB[4];
  #pragma unroll
  for (int i = 0; i < 4; ++i)
    srcB[i] = wb + (long long)eA*524288 + (size_t)(nt*128 + i*32 + grp)*1024 + sw;

  // A staging bases
  const char* srcA[4];
  const float* xrow = nullptr; int arow = 0, ach = 0;
  if (BF16A){
    const char* xb = (const char*)xbf;
    #pragma unroll
    for (int i = 0; i < 4; ++i){
      int tk = ((const int*)(sm + LTOK))[i*32 + grp];
      if (tk < 0) tk = 0;
      srcA[i] = xb + (size_t)tk*1024 + sw;
    }
  } else {
    arow = tid >> 1; ach = tid & 1;      // row, col-half (32 cols)
    int tk = ((const int*)(sm + LTOK))[arow];
    if (tk < 0) tk = 0;
    xrow = x + (size_t)tk*DDIM + ach*32;
  }
  int ldst = (w << 10);

  // prologue: u=0 -> buf 0
  #pragma unroll
  for (int i = 0; i < 4; ++i){
    load_lds16(srcB[i], sm + BBUF + i*4096 + ldst);
    if (BF16A) load_lds16(srcA[i], sm + ABUF + i*4096 + ldst);
  }
  if (!BF16A){
    uint pk[16];
    #pragma unroll
    for (int q2 = 0; q2 < 4; ++q2){
      float4 fv = *(const float4*)(xrow + q2*8);
      float4 fw = *(const float4*)(xrow + q2*8 + 4);
      pk[q2*4+0] = (uint)f2bf(fv.x) | ((uint)f2bf(fv.y) << 16);
      pk[q2*4+1] = (uint)f2bf(fv.z) | ((uint)f2bf(fv.w) << 16);
      pk[q2*4+2] = (uint)f2bf(fw.x) | ((uint)f2bf(fw.y) << 16);
      pk[q2*4+3] = (uint)f2bf(fw.z) | ((uint)f2bf(fw.w) << 16);
    }
    #pragma unroll
    for (int q2 = 0; q2 < 4; ++q2){
      int g = ach*4 + q2;
      *(uint4*)(sm + ABUF + arow*128 + ((g ^ (arow & 7)) << 4)) =
          make_uint4(pk[q2*4], pk[q2*4+1], pk[q2*4+2], pk[q2*4+3]);
    }
  }

  f32x4 acc[4][4], res[4][4];
  #pragma unroll
  for (int m=0;m<4;++m)
    #pragma unroll
    for (int n=0;n<4;++n) acc[m][n] = (f32x4){0.f,0.f,0.f,0.f};

  for (int u = 0; u < 16; ++u){
    int b = u & 1;
    asm volatile("s_waitcnt vmcnt(0)" ::: "memory");
    __syncthreads();
    int un = u + 1;
    uint pk[16];
    if (un < 16){
      int b2 = un & 1;
      long long aoff = (long long)(un & 7) * 128;
      long long boff = aoff + ((un >> 3) ? edelt : 0);
      #pragma unroll
      for (int i = 0; i < 4; ++i){
        load_lds16(srcB[i] + boff, sm + BBUF + b2*16384 + i*4096 + ldst);
        if (BF16A) load_lds16(srcA[i] + aoff, sm + ABUF + b2*16384 + i*4096 + ldst);
      }
      if (!BF16A){
        const float* xr = xrow + (un & 7)*64;
        #pragma unroll
        for (int q2 = 0; q2 < 4; ++q2){
          float4 fv = *(const float4*)(xr + q2*8);
          float4 fw = *(const float4*)(xr + q2*8 + 4);
          pk[q2*4+0] = (uint)f2bf(fv.x) | ((uint)f2bf(fv.y) << 16);
          pk[q2*4+1] = (uint)f2bf(fv.z) | ((uint)f2bf(fv.w) << 16);
          pk[q2*4+2] = (uint)f2bf(fw.x) | ((uint)f2bf(fw.y) << 16);
          pk[q2*4+3] = (uint)f2bf(fw.z) | ((uint)f2bf(fw.w) << 16);
        }
      }
    }
    const char* Ab = sm + ABUF + b*16384;
    const char* Bb = sm + BBUF + b*16384;
    bf16x8 af[4][2], bf[4][2];
    #pragma unroll
    for (int m=0;m<4;++m){
      int r = wm*64 + m*16 + (lane & 15);
      af[m][0] = readF64(Ab, r, (lane >> 4));
      af[m][1] = readF64(Ab, r, 4 + (lane >> 4));
    }
    #pragma unroll
    for (int n=0;n<4;++n){
      int r = wn*64 + n*16 + (lane & 15);
      bf[n][0] = readF64(Bb, r, (lane >> 4));
      bf[n][1] = readF64(Bb, r, 4 + (lane >> 4));
    }
    #pragma unroll
    for (int m=0;m<4;++m)
      #pragma unroll
      for (int n=0;n<4;++n){
        acc[m][n] = MFMA(af[m][0], bf[n][0], acc[m][n]);
        acc[m][n] = MFMA(af[m][1], bf[n][1], acc[m][n]);
      }
    if (!BF16A && un < 16){
      int b2 = un & 1;
      #pragma unroll
      for (int q2 = 0; q2 < 4; ++q2){
        int g = ach*4 + q2;
        *(uint4*)(sm + ABUF + b2*16384 + arow*128 + ((g ^ (arow & 7)) << 4)) =
            make_uint4(pk[q2*4], pk[q2*4+1], pk[q2*4+2], pk[q2*4+3]);
      }
    }
    if (u == 7){
      const float* bev = be + (size_t)eA*DDIM + nt*128;
      float bcol[4];
      #pragma unroll
      for (int n=0;n<4;++n) bcol[n] = bev[wn*64 + n*16 + (lane & 15)];
      #pragma unroll
      for (int m=0;m<4;++m){
        #pragma unroll
        for (int j=0;j<4;++j){
          int row = wm*64 + m*16 + ((lane >> 4) << 2) + j;
          float g = ((const float2*)(sm + LGOFF))[row].x;
          #pragma unroll
          for (int n=0;n<4;++n){
            res[m][n][j] = g * (acc[m][n][j] + bcol[n]);
            acc[m][n][j] = 0.f;
          }
        }
      }
    }
    if (u == 15){
      const float* bev = be + (size_t)eB*DDIM + nt*128;
      float bcol[4];
      #pragma unroll
      for (int n=0;n<4;++n) bcol[n] = bev[wn*64 + n*16 + (lane & 15)];
      #pragma unroll
      for (int m=0;m<4;++m){
        #pragma unroll
        for (int j=0;j<4;++j){
          int row = wm*64 + m*16 + ((lane >> 4) << 2) + j;
          int tk = ((const int*)(sm + LTOK))[row];
          float g = ((const float2*)(sm + LGOFF))[row].y;
          if (tk >= 0){
            float* orow = out + (size_t)tk*DDIM + nt*128;
            #pragma unroll
            for (int n=0;n<4;++n)
              orow[wn*64 + n*16 + (lane & 15)] = res[m][n][j] + g * (acc[m][n][j] + bcol[n]);
          }
        }
      }
    }
  }
}

// ---- host launch --------------------------------------------------------------
extern "C" void kernel_launch(void* const* d_in, const int* in_sizes, int n_in,
                              void* d_out, int out_size, void* d_ws, size_t ws_size,
                              hipStream_t stream)
{
  const float* x   = (const float*)d_in[0];
  const float* Wg1 = (const float*)d_in[1];
  const float* bg1 = (const float*)d_in[2];
  const float* Wg2 = (const float*)d_in[3];
  const float* bg2 = (const float*)d_in[4];
  const float* We  = (const float*)d_in[5];
  const float* be  = (const float*)d_in[6];
  float* out = (float*)d_out;
  char* ws = (char*)d_ws;

  ushort* Wt        = (ushort*)(ws + 0);          // 8,388,608
  ushort* W1h       = (ushort*)(ws + 8388608);    //   131,072
  ushort* W1l       = (ushort*)(ws + 8519680);    //   131,072
  char*   CTRL      = ws + 8650752;               //     8,192
  int*  refine_cnt  = (int*)(CTRL);
  int*  ntiles      = (int*)(CTRL + 4);
  int*  counts      = (int*)(CTRL + 64);          // 256 ints
  int*  cursors     = (int*)(CTRL + 2048);        // 256 ints
  int*  bases       = (int*)(CTRL + 4096);        // 257 ints
  int2*   gate_e    = (int2*)(ws + 8658944);      // 1,048,576
  float2* gate_g    = (float2*)(ws + 9707520);    // 1,048,576
  int*  refine_list = (int*)(ws + 10756096);      //   524,288
  int*  pair_tok    = (int*)(ws + 11280384);      //   524,288
  float2* pair_g    = (float2*)(ws + 11804672);   // 1,048,576
  int*  tile_pair   = (int*)(ws + 12853248);      //    10,240
  int*  tile_row0   = (int*)(ws + 12863488);      //    10,240
  const size_t XBF_OFF = 16777216ull;
  const size_t XBF_BYTES = (size_t)NTOK * DDIM * 2;   // 134 MB
  bool bf16a = ws_size >= XBF_OFF + XBF_BYTES;
  ushort* xbf = bf16a ? (ushort*)(ws + XBF_OFF) : nullptr;

  hipMemsetAsync(CTRL, 0, 8192, stream);
  hipLaunchKernelGGL(kconv,    dim3(1040), dim3(256), 0, stream, We, Wg1, Wt, W1h, W1l);
  hipLaunchKernelGGL(kgate,    dim3(2048), dim3(256), 0, stream, x, W1h, W1l, bg1, Wg2, bg2,
                     xbf, gate_e, gate_g, refine_cnt, refine_list, counts);
  hipLaunchKernelGGL(krefine,  dim3(512),  dim3(128), 0, stream, x, Wg1, bg1, Wg2, bg2,
                     refine_cnt, refine_list, gate_e, gate_g, counts);
  hipLaunchKernelGGL(kscan,    dim3(1),    dim3(64),  0, stream, counts, bases, tile_pair, tile_row0, ntiles);
  hipLaunchKernelGGL(kscatter, dim3(512),  dim3(256), 0, stream, gate_e, gate_g, bases, cursors, pair_tok, pair_g);
  if (bf16a)
    hipLaunchKernelGGL((kexpert<1>), dim3(5120), dim3(256), 0, stream, x, xbf, Wt, be, out,
                       counts, bases, tile_pair, tile_row0, ntiles, pair_tok, pair_g);
  else
    hipLaunchKernelGGL((kexpert<0>), dim3(5120), dim3(256), 0, stream, x, xbf, Wt, be, out,
                       counts, bases, tile_pair, tile_row0, ntiles, pair_tok, pair_g);
  (void)in_sizes; (void)n_in; (void)out_size; (void)ws_size;
}

// Round 3
// 446.252 us; speedup vs baseline: 1.5682x; 1.0937x over previous
//
#include <hip/hip_runtime.h>
#include <cstdint>
#include <math.h>

// MoE top-2 of 16 experts. N=131072, D=512, H=128, E=16, O=512.
// Pipeline: memset CTRL -> kconv (We->Wt bf16 [O][D], Wg1->hi/lo bf16 [H][D])
//  -> kgate (split-bf16 MFMA gating + fp64 softmax/top2 + xbf16 store + pair histogram)
//  -> krefine (fp64 exact gating for ambiguous tokens; patches pair counts)
//  -> kscan (one-wave shuffle prefix scan + tile list) -> kscatter
//  -> kexpert2 (pair-bucket GEMM, 256 tok x 256 cols, 8-phase counted-vmcnt
//     schedule, both operands via global_load_lds w/ pre-swizzled per-lane source;
//     gate-A folded into accumulator; single store, no atomics)

#define NTOK 131072
#define DDIM 512
#define NT 16          // K-tiles in kexpert2: 8 per expert x 2 experts

typedef short  bf16x8 __attribute__((ext_vector_type(8)));
typedef float  f32x4  __attribute__((ext_vector_type(4)));

__device__ __forceinline__ ushort f2bf(float f){
  uint u = __float_as_uint(f);
  u += 0x7fffu + ((u >> 16) & 1u);        // RNE
  return (ushort)(u >> 16);
}
__device__ __forceinline__ float bf2f(ushort h){ return __uint_as_float(((uint)h) << 16); }

__device__ __forceinline__ void load_lds16(const void* g, void* l){
  __builtin_amdgcn_global_load_lds(
      (const __attribute__((address_space(1))) void*)(uintptr_t)g,
      (__attribute__((address_space(3))) void*)(uintptr_t)l, 16, 0, 0);
}

__device__ __forceinline__ f32x4 MFMA(bf16x8 a, bf16x8 b, f32x4 c){
  return __builtin_amdgcn_mfma_f32_16x16x32_bf16(a, b, c, 0, 0, 0);
}

// ---- swizzled LDS helpers -----------------------------------------------------
// 64-col bf16 tile (pitch 128B): logical (row r, 16B chunk q) lives at byte
// r*128 + ((q ^ (r&7))<<4).
__device__ __forceinline__ bf16x8 readF64(const char* buf, int r, int q){
  return *(const bf16x8*)(buf + r*128 + ((q ^ (r & 7)) << 4));
}
// 32-col bf16 tile (pitch 64B)
__device__ __forceinline__ bf16x8 readF32c(const char* buf, int r, int q){
  return *(const bf16x8*)(buf + r*64 + ((q ^ (r & 3)) << 4));
}

// stage [128 rows][32 cols] bf16 (8KB) via global_load_lds; global pitch 1024B.
__device__ __forceinline__ void stageB32(const ushort* grow, char* lds, int tid){
  const char* gb = (const char*)grow;
  #pragma unroll
  for (int i = 0; i < 2; ++i){
    int lin = i*4096 + tid*16;
    int r = lin >> 6;
    int g = (lin >> 4) & 3;
    load_lds16(gb + r*1024 + ((g ^ (r & 3)) << 4), lds + i*4096 + ((tid >> 6) << 10));
  }
}

// pack 8 fp32 -> hi/lo bf16 pairs
__device__ __forceinline__ void pack8(const float* fv, uint* ph, uint* pl){
  #pragma unroll
  for (int q=0;q<4;++q){
    float f0 = fv[2*q], f1 = fv[2*q+1];
    ushort h0 = f2bf(f0), h1 = f2bf(f1);
    ushort s0 = f2bf(f0 - bf2f(h0)), s1 = f2bf(f1 - bf2f(h1));
    ph[q] = (uint)h0 | ((uint)h1 << 16);
    pl[q] = (uint)s0 | ((uint)s1 << 16);
  }
}
__device__ __forceinline__ void writeA2p(char* hbuf, char* lbuf, int ar, int acq,
                                         const uint* ph, const uint* pl){
  int off = ar*64 + ((acq ^ (ar & 3)) << 4);
  *(uint4*)(hbuf + off) = make_uint4(ph[0],ph[1],ph[2],ph[3]);
  *(uint4*)(lbuf + off) = make_uint4(pl[0],pl[1],pl[2],pl[3]);
}

// ---- kconv: We [E][D][O] f32 -> Wt [E][O][D] bf16 ; Wg1 [D][H] f32 -> W1h/W1l [H][D] bf16
__global__ void kconv(const float* __restrict__ We, const float* __restrict__ Wg1,
                      ushort* __restrict__ Wt, ushort* __restrict__ W1h, ushort* __restrict__ W1l){
  __shared__ float sh[64*65];
  int bx = blockIdx.x, tid = threadIdx.x;
  if (bx < 1024){
    int e = bx >> 6, dt = (bx >> 3) & 7, ot = bx & 7;
    const float* src = We + (size_t)e*262144 + (size_t)dt*64*512 + ot*64;
    #pragma unroll
    for (int it=0; it<16; ++it){ int idx = it*256+tid; int dl = idx>>6, ol = idx&63;
      sh[dl*65+ol] = src[dl*512+ol]; }
    __syncthreads();
    ushort* dst = Wt + (size_t)e*262144 + (size_t)ot*64*512 + dt*64;
    #pragma unroll
    for (int it=0; it<16; ++it){ int idx = it*256+tid; int ol = idx>>6, dl = idx&63;
      dst[(size_t)ol*512+dl] = f2bf(sh[dl*65+ol]); }
  } else {
    int q = bx - 1024;
    int dt = q >> 1, ht = q & 1;
    const float* src = Wg1 + (size_t)dt*64*128 + ht*64;
    #pragma unroll
    for (int it=0; it<16; ++it){ int idx = it*256+tid; int dl = idx>>6, ol = idx&63;
      sh[dl*65+ol] = src[dl*128+ol]; }
    __syncthreads();
    #pragma unroll
    for (int it=0; it<16; ++it){ int idx = it*256+tid; int ol = idx>>6, dl = idx&63;
      float wv = sh[dl*65+ol];
      ushort hi = f2bf(wv);
      ushort lo = f2bf(wv - bf2f(hi));
      size_t o = (size_t)(ht*64+ol)*512 + dt*64+dl;
      W1h[o] = hi; W1l[o] = lo; }
  }
}

// ---- kgate: fused gating + xbf16 producer + pair histogram.
__global__ __launch_bounds__(256) void kgate(
    const float* __restrict__ x, const ushort* __restrict__ W1h, const ushort* __restrict__ W1l,
    const float* __restrict__ bg1, const float* __restrict__ Wg2, const float* __restrict__ bg2,
    ushort* __restrict__ xbf,
    int2* __restrict__ gate_e, float2* __restrict__ gate_g,
    int* __restrict__ refine_cnt, int* __restrict__ refine_list, int* __restrict__ counts)
{
  __shared__ __align__(16) char sm[49152];
  const int BOFF = 16384;
  int tid = threadIdx.x, bid = blockIdx.x;
  int lane = tid & 63, w = tid >> 6, wm = w >> 1, wn = w & 1;
  int t0 = bid * 64;
  int ar = tid >> 2, acq = tid & 3;
  const float* xrow = x + (size_t)(t0 + ar) * DDIM;
  char* xbfb = (char*)xbf;
  f32x4 acc[2][4];
  #pragma unroll
  for (int n=0;n<4;++n){
    float bb = bg1[wn*64 + n*16 + (lane & 15)];
    f32x4 z = {bb, bb, bb, bb};
    acc[0][n] = z; acc[1][n] = z;
  }
  stageB32(W1h, sm + BOFF, tid);
  stageB32(W1l, sm + BOFF + 8192, tid);
  {
    float fv[8];
    *(float4*)&fv[0] = *(const float4*)(xrow + acq*8);
    *(float4*)&fv[4] = *(const float4*)(xrow + acq*8 + 4);
    uint ph[4], pl[4];
    pack8(fv, ph, pl);
    if (xbf) *(uint4*)(xbfb + (size_t)(t0+ar)*1024 + acq*16) = make_uint4(ph[0],ph[1],ph[2],ph[3]);
    writeA2p(sm, sm + 4096, ar, acq, ph, pl);
  }
  for (int ks = 0; ks < 16; ++ks){
    int b = ks & 1;
    asm volatile("s_waitcnt vmcnt(0)" ::: "memory");
    __syncthreads();
    uint ph[4], pl[4];
    if (ks < 15){
      int k2 = ks + 1, b2 = k2 & 1;
      stageB32(W1h + k2*32, sm + BOFF + b2*16384, tid);
      stageB32(W1l + k2*32, sm + BOFF + b2*16384 + 8192, tid);
      float fv[8];
      *(float4*)&fv[0] = *(const float4*)(xrow + k2*32 + acq*8);
      *(float4*)&fv[4] = *(const float4*)(xrow + k2*32 + acq*8 + 4);
      pack8(fv, ph, pl);
      if (xbf) *(uint4*)(xbfb + (size_t)(t0+ar)*1024 + k2*64 + acq*16) = make_uint4(ph[0],ph[1],ph[2],ph[3]);
    }
    const char* Ah = sm + b*8192;
    const char* Al = Ah + 4096;
    const char* Bh = sm + BOFF + b*16384;
    const char* Bl = Bh + 8192;
    bf16x8 ah[2], alv[2], bh[4], blv[4];
    #pragma unroll
    for (int m=0;m<2;++m){
      int r = wm*32 + m*16 + (lane & 15);
      ah[m]  = readF32c(Ah, r, lane >> 4);
      alv[m] = readF32c(Al, r, lane >> 4);
    }
    #pragma unroll
    for (int n=0;n<4;++n){
      int r = wn*64 + n*16 + (lane & 15);
      bh[n]  = readF32c(Bh, r, lane >> 4);
      blv[n] = readF32c(Bl, r, lane >> 4);
    }
    #pragma unroll
    for (int m=0;m<2;++m)
      #pragma unroll
      for (int n=0;n<4;++n){
        acc[m][n] = MFMA(ah[m],  bh[n],  acc[m][n]);
        acc[m][n] = MFMA(ah[m],  blv[n], acc[m][n]);
        acc[m][n] = MFMA(alv[m], bh[n],  acc[m][n]);
      }
    if (ks < 15){
      int b2 = (ks + 1) & 1;
      writeA2p(sm + b2*8192, sm + b2*8192 + 4096, ar, acq, ph, pl);
    }
  }
  __syncthreads();
  float* hl = (float*)sm;
  #pragma unroll
  for (int m=0;m<2;++m)
    #pragma unroll
    for (int n=0;n<4;++n)
      #pragma unroll
      for (int j=0;j<4;++j){
        int row = wm*32 + m*16 + ((lane >> 4) << 2) + j;
        int col = wn*64 + n*16 + (lane & 15);
        float uv = acc[m][n][j];
        hl[row*132 + col] = 0.5f * uv * (1.0f + erff(uv * 0.70710678118654752f));
      }
  __syncthreads();
  {
    int tt = tid >> 2, cc = tid & 3;
    float4 bb = *(const float4*)(bg2 + cc*4);
    float l0 = bb.x, l1 = bb.y, l2 = bb.z, l3 = bb.w;
    const float* hrow = hl + tt*132;
    #pragma unroll 8
    for (int i = 0; i < 128; ++i){
      float hv = hrow[i];
      float4 wv = *(const float4*)(Wg2 + i*16 + cc*4);
      l0 += hv*wv.x; l1 += hv*wv.y; l2 += hv*wv.z; l3 += hv*wv.w;
    }
    float* ll = (float*)(sm + 33792);
    *(float4*)(ll + tt*16 + cc*4) = make_float4(l0, l1, l2, l3);
  }
  int* hist = (int*)(sm + 40960);
  hist[tid] = 0;
  __syncthreads();
  if (tid < 64){
    int t = t0 + tid;
    const float* l = (const float*)(sm + 33792) + tid*16;
    float b1 = -1e30f, b2 = -1e30f, b3 = -1e30f; int e1 = 0, e2 = 0;
    #pragma unroll
    for (int e = 0; e < 16; ++e){
      float v = l[e];
      if (v > b1){ b3 = b2; b2 = b1; e2 = e1; b1 = v; e1 = e; }
      else if (v > b2){ b3 = b2; b2 = v; e2 = e; }
      else if (v > b3){ b3 = v; }
    }
    double s = 0.0;
    #pragma unroll
    for (int e = 0; e < 16; ++e) s += exp((double)l[e] - (double)b1);
    double inv = 1.0 / s;
    gate_e[t] = make_int2(e1, e2);
    gate_g[t] = make_float2((float)(inv + 1e-4), (float)(exp((double)b2 - (double)b1) * inv + 1e-4));
    if (b2 - b3 < 2e-4f){
      int pos = atomicAdd(refine_cnt, 1);
      refine_list[pos] = t;
    }
    int pa = min(e1, e2), pb = max(e1, e2);
    atomicAdd(&hist[pa*16 + pb], 1);
  }
  __syncthreads();
  if (hist[tid]) atomicAdd(&counts[tid], hist[tid]);
}

// ---- krefine: exact fp64 gating for flagged tokens; patches pair counts.
__global__ __launch_bounds__(128) void krefine(
    const float* __restrict__ x, const float* __restrict__ Wg1, const float* __restrict__ bg1,
    const float* __restrict__ Wg2, const float* __restrict__ bg2,
    const int* __restrict__ refine_cnt, const int* __restrict__ refine_list,
    int2* __restrict__ gate_e, float2* __restrict__ gate_g, int* __restrict__ counts)
{
  __shared__ float  xs[512];
  __shared__ double hd[128];
  __shared__ double ld[16];
  int tid = threadIdx.x;
  int rc = *refine_cnt;
  for (int i = blockIdx.x; i < rc; i += gridDim.x){
    __syncthreads();
    int t = refine_list[i];
    *(float4*)(xs + tid*4) = *(const float4*)(x + (size_t)t*DDIM + tid*4);
    __syncthreads();
    double a = (double)bg1[tid];
    for (int d = 0; d < 512; ++d) a += (double)xs[d] * (double)Wg1[d*128 + tid];
    hd[tid] = 0.5 * a * (1.0 + erf(a * 0.70710678118654752440));
    __syncthreads();
    if (tid < 16){
      double s = (double)bg2[tid];
      for (int k = 0; k < 128; ++k) s += hd[k] * (double)Wg2[k*16 + tid];
      ld[tid] = s;
    }
    __syncthreads();
    if (tid == 0){
      int2 olde = gate_e[t];
      double b1 = -1e300, b2 = -1e300; int e1 = 0, e2 = 0;
      for (int e = 0; e < 16; ++e){
        double v = ld[e];
        if (v > b1){ b2 = b1; e2 = e1; b1 = v; e1 = e; }
        else if (v > b2){ b2 = v; e2 = e; }
      }
      double s = 0.0;
      for (int e = 0; e < 16; ++e) s += exp(ld[e] - b1);
      double inv = 1.0 / s;
      int oldp = min(olde.x, olde.y)*16 + max(olde.x, olde.y);
      int newp = min(e1, e2)*16 + max(e1, e2);
      if (oldp != newp){ atomicSub(&counts[oldp], 1); atomicAdd(&counts[newp], 1); }
      gate_e[t] = make_int2(e1, e2);
      gate_g[t] = make_float2((float)(inv + 1e-4), (float)(exp(b2 - b1) * inv + 1e-4));
    }
  }
}

// ---- kscan: one wave. prefix over 256 pair counts + tile list (ts-row tiles).
__global__ void kscan(const int* __restrict__ counts, int* __restrict__ bases,
                      int* __restrict__ tile_pair, int* __restrict__ tile_row0, int* __restrict__ ntiles,
                      int ts){
  int l = threadIdx.x;
  int4 c = *(const int4*)(counts + l*4);
  int s = c.x + c.y + c.z + c.w;
  int ps = s;
  #pragma unroll
  for (int d = 1; d < 64; d <<= 1){ int v = __shfl_up(ps, d); if (l >= d) ps += v; }
  int ex = ps - s;
  bases[4*l+0] = ex;
  bases[4*l+1] = ex + c.x;
  bases[4*l+2] = ex + c.x + c.y;
  bases[4*l+3] = ex + c.x + c.y + c.z;
  if (l == 63) bases[256] = ex + s;
  int t0 = (c.x + ts-1) / ts, t1 = (c.y + ts-1) / ts, t2 = (c.z + ts-1) / ts, t3 = (c.w + ts-1) / ts;
  int tsum = t0 + t1 + t2 + t3;
  int pt = tsum;
  #pragma unroll
  for (int d = 1; d < 64; d <<= 1){ int v = __shfl_up(pt, d); if (l >= d) pt += v; }
  int ext = pt - tsum;
  if (l == 63) *ntiles = ext + tsum;
  int tb = ext;
  int cc[4] = {c.x, c.y, c.z, c.w};
  #pragma unroll
  for (int j = 0; j < 4; ++j){
    int pp = 4*l + j;
    for (int r = 0; r < cc[j]; r += ts){ tile_pair[tb] = pp; tile_row0[tb] = r; ++tb; }
  }
}

__global__ void kscatter(const int2* __restrict__ gate_e, const float2* __restrict__ gate_g,
                         const int* __restrict__ bases, int* __restrict__ cursors,
                         int* __restrict__ pair_tok, float2* __restrict__ pair_g){
  __shared__ int h[256];
  __shared__ int gb[256];
  int tid = threadIdx.x;
  h[tid] = 0; __syncthreads();
  int t = blockIdx.x*256 + tid;
  int2 ee = gate_e[t]; float2 gg = gate_g[t];
  int a, b; float ga, gbv;
  if (ee.x < ee.y){ a = ee.x; b = ee.y; ga = gg.x; gbv = gg.y; }
  else            { a = ee.y; b = ee.x; ga = gg.y; gbv = gg.x; }
  int p = a*16 + b;
  int off = atomicAdd(&h[p], 1);
  __syncthreads();
  if (h[tid]) gb[tid] = bases[tid] + atomicAdd(&cursors[tid], h[tid]);
  __syncthreads();
  int slot = gb[p] + off;
  pair_tok[slot] = t;
  pair_g[slot] = make_float2(ga, gbv);
}

// ======== kexpert2: 256x256 pair-bucket GEMM, 8-phase counted-vmcnt schedule ====
// 512 thr = 8 waves (2M x 4N); per-wave 128 rows x 64 cols; acc[8][4] f32x4.
// LDS: A dbuf 2x32KB (2 halves of 128rx64c) + B dbuf 2x32KB + token/gate lists.
// K-tiles t=0..15: t<8 expert eA (ks=t), t>=8 expert eB (ks=t-8); A source repeats.
// Gate fold: after t=7, acc *= gA/gB; store gB*acc + gA*bA + gB*bB.
#define SBAR0 __builtin_amdgcn_sched_barrier(0)
#define BARR  do{ asm volatile("" ::: "memory"); SBAR0; __builtin_amdgcn_s_barrier(); SBAR0; asm volatile("" ::: "memory"); }while(0)

#define RDA(hp, mb) do{ \
  _Pragma("unroll") for (int m_=0;m_<4;++m_){ \
    int r_ = ((mb)+m_)*16 + l15; \
    af[m_][0] = readF64(hp, r_, l4); \
    af[m_][1] = readF64(hp, r_, 4+l4); }}while(0)
#define RDB(hp, bv, nb) do{ \
  _Pragma("unroll") for (int n_=0;n_<2;++n_){ \
    int r_ = bln + ((nb)+n_)*16 + l15; \
    bv[n_][0] = readF64(hp, r_, l4); \
    bv[n_][1] = readF64(hp, r_, 4+l4); }}while(0)
#define MMAC(bv, mb, nb) do{ \
  __builtin_amdgcn_s_setprio(1); \
  _Pragma("unroll") for (int m_=0;m_<4;++m_){ \
    _Pragma("unroll") for (int n_=0;n_<2;++n_){ \
      acc[(mb)+m_][(nb)+n_] = MFMA(af[m_][0], bv[n_][0], acc[(mb)+m_][(nb)+n_]); \
      acc[(mb)+m_][(nb)+n_] = MFMA(af[m_][1], bv[n_][1], acc[(mb)+m_][(nb)+n_]); }} \
  __builtin_amdgcn_s_setprio(0); \
}while(0)

__global__ __launch_bounds__(512, 2) void kexpert2(
    const ushort* __restrict__ xbf, const ushort* __restrict__ Wt, const float* __restrict__ be,
    float* __restrict__ out,
    const int* __restrict__ counts, const int* __restrict__ bases,
    const int* __restrict__ tile_pair, const int* __restrict__ tile_row0, const int* __restrict__ ntiles,
    const int* __restrict__ pair_tok, const float2* __restrict__ pair_g)
{
  __shared__ __align__(16) char sm[134144];
  const int BBASE = 65536, LTOK = 131072, LG = 132096;
  int bid = blockIdx.x;
  int tile = ((bid >> 4) << 3) | (bid & 7);   // col-block pair shares XCD
  int nt = (bid >> 3) & 1;
  if (tile >= *ntiles) return;
  int p = tile_pair[tile], row0 = tile_row0[tile];
  int base = bases[p], cnt = counts[p];
  int eA = p >> 4, eB = p & 15;
  int tid = threadIdx.x, lane = tid & 63, w = tid >> 6;
  int wm = w >> 2, wn = w & 3;
  int l15 = lane & 15, l4 = lane >> 4;
  int bln = (wn & 1) * 64;
  if (tid < 256){
    int rr = row0 + tid; bool v = rr < cnt;
    ((int*)(sm + LTOK))[tid] = v ? pair_tok[base + rr] : -1;
    ((float2*)(sm + LG))[tid] = v ? pair_g[base + rr] : make_float2(0.f, 1.f);
  }
  __syncthreads();

  int rr0 = tid >> 3;
  int sw = ((tid & 7) ^ (rr0 & 7)) << 4;
  const char* xb = (const char*)xbf;
  const char* srcA[2][2];
  #pragma unroll
  for (int h = 0; h < 2; ++h)
    #pragma unroll
    for (int i = 0; i < 2; ++i){
      int tk = ((const int*)(sm + LTOK))[h*128 + i*64 + rr0];
      if (tk < 0) tk = 0;
      srcA[h][i] = xb + (size_t)tk*1024 + sw;
    }
  const char* srcB0 = (const char*)Wt + (size_t)eA*524288 + (size_t)(nt*256 + rr0)*1024 + sw;
  long long edelt = ((long long)eB - eA) * 524288;
  char* dA = sm + w*1024;
  char* dB = sm + BBASE + w*1024;

  auto stA = [&](int t, int h){
    if (t >= NT) return;
    int ks = t & 7, bf_ = t & 1;
    load_lds16(srcA[h][0] + ks*128, dA + bf_*32768 + h*16384);
    load_lds16(srcA[h][1] + ks*128, dA + bf_*32768 + h*16384 + 8192);
  };
  auto stB = [&](int t, int h){
    if (t >= NT) return;
    int ks = t & 7, bf_ = t & 1;
    long long eo = ((t >= 8) ? edelt : 0) + ks*128;
    load_lds16(srcB0 + h*131072 + eo,         dB + bf_*32768 + h*16384);
    load_lds16(srcB0 + h*131072 + 65536 + eo, dB + bf_*32768 + h*16384 + 8192);
  };

  const char* A0 = sm + wm*16384;            // buf0 A, this wave's half
  const char* A1 = A0 + 32768;               // buf1
  const char* B0 = sm + BBASE + (wn >> 1)*16384;
  const char* B1 = B0 + 32768;

  f32x4 acc[8][4];
  #pragma unroll
  for (int m = 0; m < 8; ++m)
    #pragma unroll
    for (int n = 0; n < 4; ++n) acc[m][n] = (f32x4){0.f,0.f,0.f,0.f};

  // prologue: tile0 (A+B) + tile1 (B); tile1's A staged in ph1/2 of iter 0
  stA(0,0); stA(0,1); stB(0,0); stB(0,1); stB(1,0); stB(1,1);
  asm volatile("s_waitcnt vmcnt(4)" ::: "memory");
  BARR;

  bf16x8 af[4][2], bL[2][2], bH[2][2];
  #pragma unroll 1
  for (int i = 0; i < 8; ++i){
    int t0 = 2*i, t1 = t0 + 1;
    // ph1: Q(m0-3, n0-1)
    RDA(A0, 0); RDB(B0, bL, 0); stA(t1, 0);
    BARR; MMAC(bL, 0, 0); BARR;
    // ph2: Q(m0-3, n2-3)
    RDB(B0, bH, 2); stA(t1, 1);
    BARR; MMAC(bH, 0, 2); BARR;
    // ph3: Q(m4-7, n2-3)
    RDA(A0, 4); stB(t0+2, 0);
    BARR; MMAC(bH, 4, 2); BARR;
    // ph4: Q(m4-7, n0-1)
    stB(t0+2, 1);
    if (i != 7) { asm volatile("s_waitcnt vmcnt(4)" ::: "memory"); }
    else        { asm volatile("s_waitcnt vmcnt(0)" ::: "memory"); }
    BARR; MMAC(bL, 4, 0); BARR;
    // ph5: buf1 Q(m0-3, n0-1)
    RDA(A1, 0); RDB(B1, bL, 0); stA(t0+2, 0);
    BARR; MMAC(bL, 0, 0); BARR;
    // ph6
    RDB(B1, bH, 2); stA(t0+2, 1);
    BARR; MMAC(bH, 0, 2); BARR;
    // ph7
    RDA(A1, 4); stB(t1+2, 0);
    BARR; MMAC(bH, 4, 2); BARR;
    // ph8
    stB(t1+2, 1);
    if (i != 7) { asm volatile("s_waitcnt vmcnt(4)" ::: "memory"); }
    BARR; MMAC(bL, 4, 0); BARR;
    if (i == 3){            // expert switch: fold gate-A into accumulator
      #pragma unroll
      for (int m = 0; m < 8; ++m)
        #pragma unroll
        for (int j = 0; j < 4; ++j){
          int row = wm*128 + m*16 + l4*4 + j;
          float2 g2 = ((const float2*)(sm + LG))[row];
          float r_ = g2.x / g2.y;
          #pragma unroll
          for (int n = 0; n < 4; ++n) acc[m][n][j] *= r_;
        }
    }
  }

  // epilogue: out = gB*acc + gA*bA + gB*bB
  float bcA[4], bcB[4];
  #pragma unroll
  for (int n = 0; n < 4; ++n){
    int col = nt*256 + wn*64 + n*16 + l15;
    bcA[n] = be[(size_t)eA*DDIM + col];
    bcB[n] = be[(size_t)eB*DDIM + col];
  }
  #pragma unroll
  for (int m = 0; m < 8; ++m)
    #pragma unroll
    for (int j = 0; j < 4; ++j){
      int row = wm*128 + m*16 + l4*4 + j;
      int tk = ((const int*)(sm + LTOK))[row];
      if (tk >= 0){
        float2 g2 = ((const float2*)(sm + LG))[row];
        float* orow = out + (size_t)tk*DDIM + nt*256 + wn*64;
        #pragma unroll
        for (int n = 0; n < 4; ++n)
          orow[n*16 + l15] = g2.y*acc[m][n][j] + g2.x*bcA[n] + g2.y*bcB[n];
      }
    }
}

// ---- kexpertF: fallback (no xbf room): 128x128 pair-bucket GEMM, fp32-A reg-staged.
__global__ __launch_bounds__(256, 2) void kexpertF(
    const float* __restrict__ x,
    const ushort* __restrict__ Wt, const float* __restrict__ be,
    float* __restrict__ out,
    const int* __restrict__ counts, const int* __restrict__ bases,
    const int* __restrict__ tile_pair, const int* __restrict__ tile_row0, const int* __restrict__ ntiles,
    const int* __restrict__ pair_tok, const float2* __restrict__ pair_g)
{
  __shared__ __align__(16) char sm[67072];
  const int ABUF = 0, BBUF = 32768, LTOK = 65536, LGOFF = 66048;
  int tile = blockIdx.x >> 2, nt = blockIdx.x & 3;
  if (tile >= *ntiles) return;
  int p = tile_pair[tile], row0 = tile_row0[tile];
  int base = bases[p], cnt = counts[p];
  int eA = p >> 4, eB = p & 15;
  int tid = threadIdx.x, lane = tid & 63;
  int w = tid >> 6, wm = w >> 1, wn = w & 1;
  if (tid < 128){
    int rr = row0 + tid; bool v = rr < cnt;
    ((int*)(sm + LTOK))[tid] = v ? pair_tok[base + rr] : -1;
    ((float2*)(sm + LGOFF))[tid] = v ? pair_g[base + rr] : make_float2(0.f, 0.f);
  }
  __syncthreads();
  const char* wb = (const char*)Wt;
  int grp = tid >> 3, gch = tid & 7;
  int swz = (gch ^ (grp & 7)) << 4;
  long long edelt = ((long long)eB - (long long)eA) * 524288;
  const char* srcB[4];
  #pragma unroll
  for (int i = 0; i < 4; ++i)
    srcB[i] = wb + (long long)eA*524288 + (size_t)(nt*128 + i*32 + grp)*1024 + swz;
  int arow = tid >> 1, ach = tid & 1;
  int tkr = ((const int*)(sm + LTOK))[arow];
  if (tkr < 0) tkr = 0;
  const float* xrow = x + (size_t)tkr*DDIM + ach*32;
  int ldst = (w << 10);
  #pragma unroll
  for (int i = 0; i < 4; ++i) load_lds16(srcB[i], sm + BBUF + i*4096 + ldst);
  {
    uint pk[16];
    #pragma unroll
    for (int q2 = 0; q2 < 4; ++q2){
      float4 fv = *(const float4*)(xrow + q2*8);
      float4 fw = *(const float4*)(xrow + q2*8 + 4);
      pk[q2*4+0] = (uint)f2bf(fv.x) | ((uint)f2bf(fv.y) << 16);
      pk[q2*4+1] = (uint)f2bf(fv.z) | ((uint)f2bf(fv.w) << 16);
      pk[q2*4+2] = (uint)f2bf(fw.x) | ((uint)f2bf(fw.y) << 16);
      pk[q2*4+3] = (uint)f2bf(fw.z) | ((uint)f2bf(fw.w) << 16);
    }
    #pragma unroll
    for (int q2 = 0; q2 < 4; ++q2){
      int g = ach*4 + q2;
      *(uint4*)(sm + ABUF + arow*128 + ((g ^ (arow & 7)) << 4)) =
          make_uint4(pk[q2*4], pk[q2*4+1], pk[q2*4+2], pk[q2*4+3]);
    }
  }
  f32x4 acc[4][4], res[4][4];
  #pragma unroll
  for (int m=0;m<4;++m)
    #pragma unroll
    for (int n=0;n<4;++n) acc[m][n] = (f32x4){0.f,0.f,0.f,0.f};
  for (int u = 0; u < 16; ++u){
    int b = u & 1;
    asm volatile("s_waitcnt vmcnt(0)" ::: "memory");
    __syncthreads();
    int un = u + 1;
    uint pk[16];
    if (un < 16){
      int b2 = un & 1;
      long long aoff = (long long)(un & 7) * 128;
      long long boff = aoff + ((un >> 3) ? edelt : 0);
      #pragma unroll
      for (int i = 0; i < 4; ++i)
        load_lds16(srcB[i] + boff, sm + BBUF + b2*16384 + i*4096 + ldst);
      const float* xr = xrow + (un & 7)*64;
      #pragma unroll
      for (int q2 = 0; q2 < 4; ++q2){
        float4 fv = *(const float4*)(xr + q2*8);
        float4 fw = *(const float4*)(xr + q2*8 + 4);
        pk[q2*4+0] = (uint)f2bf(fv.x) | ((uint)f2bf(fv.y) << 16);
        pk[q2*4+1] = (uint)f2bf(fv.z) | ((uint)f2bf(fv.w) << 16);
        pk[q2*4+2] = (uint)f2bf(fw.x) | ((uint)f2bf(fw.y) << 16);
        pk[q2*4+3] = (uint)f2bf(fw.z) | ((uint)f2bf(fw.w) << 16);
      }
    }
    const char* Ab = sm + ABUF + b*16384;
    const char* Bb = sm + BBUF + b*16384;
    bf16x8 af2[4][2], bf2[4][2];
    #pragma unroll
    for (int m=0;m<4;++m){
      int r = wm*64 + m*16 + (lane & 15);
      af2[m][0] = readF64(Ab, r, (lane >> 4));
      af2[m][1] = readF64(Ab, r, 4 + (lane >> 4));
    }
    #pragma unroll
    for (int n=0;n<4;++n){
      int r = wn*64 + n*16 + (lane & 15);
      bf2[n][0] = readF64(Bb, r, (lane >> 4));
      bf2[n][1] = readF64(Bb, r, 4 + (lane >> 4));
    }
    #pragma unroll
    for (int m=0;m<4;++m)
      #pragma unroll
      for (int n=0;n<4;++n){
        acc[m][n] = MFMA(af2[m][0], bf2[n][0], acc[m][n]);
        acc[m][n] = MFMA(af2[m][1], bf2[n][1], acc[m][n]);
      }
    if (un < 16){
      int b2 = un & 1;
      #pragma unroll
      for (int q2 = 0; q2 < 4; ++q2){
        int g = ach*4 + q2;
        *(uint4*)(sm + ABUF + b2*16384 + arow*128 + ((g ^ (arow & 7)) << 4)) =
            make_uint4(pk[q2*4], pk[q2*4+1], pk[q2*4+2], pk[q2*4+3]);
      }
    }
    if (u == 7){
      const float* bev = be + (size_t)eA*DDIM + nt*128;
      float bcol[4];
      #pragma unroll
      for (int n=0;n<4;++n) bcol[n] = bev[wn*64 + n*16 + (lane & 15)];
      #pragma unroll
      for (int m=0;m<4;++m)
        #pragma unroll
        for (int j=0;j<4;++j){
          int row = wm*64 + m*16 + ((lane >> 4) << 2) + j;
          float g = ((const float2*)(sm + LGOFF))[row].x;
          #pragma unroll
          for (int n=0;n<4;++n){
            res[m][n][j] = g * (acc[m][n][j] + bcol[n]);
            acc[m][n][j] = 0.f;
          }
        }
    }
    if (u == 15){
      const float* bev = be + (size_t)eB*DDIM + nt*128;
      float bcol[4];
      #pragma unroll
      for (int n=0;n<4;++n) bcol[n] = bev[wn*64 + n*16 + (lane & 15)];
      #pragma unroll
      for (int m=0;m<4;++m)
        #pragma unroll
        for (int j=0;j<4;++j){
          int row = wm*64 + m*16 + ((lane >> 4) << 2) + j;
          int tk = ((const int*)(sm + LTOK))[row];
          float g = ((const float2*)(sm + LGOFF))[row].y;
          if (tk >= 0){
            float* orow = out + (size_t)tk*DDIM + nt*128;
            #pragma unroll
            for (int n=0;n<4;++n)
              orow[wn*64 + n*16 + (lane & 15)] = res[m][n][j] + g * (acc[m][n][j] + bcol[n]);
          }
        }
    }
  }
}

// ---- host launch --------------------------------------------------------------
extern "C" void kernel_launch(void* const* d_in, const int* in_sizes, int n_in,
                              void* d_out, int out_size, void* d_ws, size_t ws_size,
                              hipStream_t stream)
{
  const float* x   = (const float*)d_in[0];
  const float* Wg1 = (const float*)d_in[1];
  const float* bg1 = (const float*)d_in[2];
  const float* Wg2 = (const float*)d_in[3];
  const float* bg2 = (const float*)d_in[4];
  const float* We  = (const float*)d_in[5];
  const float* be  = (const float*)d_in[6];
  float* out = (float*)d_out;
  char* ws = (char*)d_ws;

  ushort* Wt        = (ushort*)(ws + 0);          // 8,388,608
  ushort* W1h       = (ushort*)(ws + 8388608);    //   131,072
  ushort* W1l       = (ushort*)(ws + 8519680);    //   131,072
  char*   CTRL      = ws + 8650752;               //     8,192
  int*  refine_cnt  = (int*)(CTRL);
  int*  ntiles      = (int*)(CTRL + 4);
  int*  counts      = (int*)(CTRL + 64);          // 256 ints
  int*  cursors     = (int*)(CTRL + 2048);        // 256 ints
  int*  bases       = (int*)(CTRL + 4096);        // 257 ints
  int2*   gate_e    = (int2*)(ws + 8658944);      // 1,048,576
  float2* gate_g    = (float2*)(ws + 9707520);    // 1,048,576
  int*  refine_list = (int*)(ws + 10756096);      //   524,288
  int*  pair_tok    = (int*)(ws + 11280384);      //   524,288
  float2* pair_g    = (float2*)(ws + 11804672);   // 1,048,576
  int*  tile_pair   = (int*)(ws + 12853248);      //    10,240
  int*  tile_row0   = (int*)(ws + 12863488);      //    10,240
  const size_t XBF_OFF = 16777216ull;
  const size_t XBF_BYTES = (size_t)NTOK * DDIM * 2;   // 134 MB
  bool bf16a = ws_size >= XBF_OFF + XBF_BYTES;
  ushort* xbf = bf16a ? (ushort*)(ws + XBF_OFF) : nullptr;

  hipMemsetAsync(CTRL, 0, 8192, stream);
  hipLaunchKernelGGL(kconv,    dim3(1040), dim3(256), 0, stream, We, Wg1, Wt, W1h, W1l);
  hipLaunchKernelGGL(kgate,    dim3(2048), dim3(256), 0, stream, x, W1h, W1l, bg1, Wg2, bg2,
                     xbf, gate_e, gate_g, refine_cnt, refine_list, counts);
  hipLaunchKernelGGL(krefine,  dim3(512),  dim3(128), 0, stream, x, Wg1, bg1, Wg2, bg2,
                     refine_cnt, refine_list, gate_e, gate_g, counts);
  hipLaunchKernelGGL(kscan,    dim3(1),    dim3(64),  0, stream, counts, bases, tile_pair, tile_row0, ntiles,
                     bf16a ? 256 : 128);
  hipLaunchKernelGGL(kscatter, dim3(512),  dim3(256), 0, stream, gate_e, gate_g, bases, cursors, pair_tok, pair_g);
  if (bf16a)
    hipLaunchKernelGGL(kexpert2, dim3(1408), dim3(512), 0, stream, xbf, Wt, be, out,
                       counts, bases, tile_pair, tile_row0, ntiles, pair_tok, pair_g);
  else
    hipLaunchKernelGGL(kexpertF, dim3(5120), dim3(256), 0, stream, x, Wt, be, out,
                       counts, bases, tile_pair, tile_row0, ntiles, pair_tok, pair_g);
  (void)in_sizes; (void)n_in; (void)out_size; (void)ws_size;
}

// Round 4
// 445.359 us; speedup vs baseline: 1.5713x; 1.0020x over previous
//
#include <hip/hip_runtime.h>
#include <cstdint>
#include <math.h>

// MoE top-2 of 16 experts. N=131072, D=512, H=128, E=16, O=512.
// Pipeline: memset CTRL -> kconv (We->Wt bf16 [O][D], Wg1->hi/lo bf16 [H][D])
//  -> kgate (split-bf16 MFMA gating + fp64 softmax/top2 + xbf16 store + pair histogram)
//  -> krefine (fp64 exact gating for ambiguous tokens; patches pair counts)
//  -> kscan (one-wave shuffle prefix scan + tile list) -> kscatter
//  -> kexpert2 (pair-bucket GEMM, 256 tok x 256 cols, 8-phase counted-vmcnt
//     schedule with RAW barriers (no "memory" clobbers -> compiler must not
//     re-insert vmcnt(0) drains); gate-A folded into accumulator; single store)

#define NTOK 131072
#define DDIM 512
#define NT 16          // K-tiles in kexpert2: 8 per expert x 2 experts

typedef short  bf16x8 __attribute__((ext_vector_type(8)));
typedef float  f32x4  __attribute__((ext_vector_type(4)));

__device__ __forceinline__ ushort f2bf(float f){
  uint u = __float_as_uint(f);
  u += 0x7fffu + ((u >> 16) & 1u);        // RNE
  return (ushort)(u >> 16);
}
__device__ __forceinline__ float bf2f(ushort h){ return __uint_as_float(((uint)h) << 16); }

__device__ __forceinline__ void load_lds16(const void* g, void* l){
  __builtin_amdgcn_global_load_lds(
      (const __attribute__((address_space(1))) void*)(uintptr_t)g,
      (__attribute__((address_space(3))) void*)(uintptr_t)l, 16, 0, 0);
}

__device__ __forceinline__ f32x4 MFMA(bf16x8 a, bf16x8 b, f32x4 c){
  return __builtin_amdgcn_mfma_f32_16x16x32_bf16(a, b, c, 0, 0, 0);
}

// ---- swizzled LDS helpers -----------------------------------------------------
// 64-col bf16 tile (pitch 128B): logical (row r, 16B chunk q) lives at byte
// r*128 + ((q ^ (r&7))<<4).
__device__ __forceinline__ bf16x8 readF64(const char* buf, int r, int q){
  return *(const bf16x8*)(buf + r*128 + ((q ^ (r & 7)) << 4));
}
// 32-col bf16 tile (pitch 64B)
__device__ __forceinline__ bf16x8 readF32c(const char* buf, int r, int q){
  return *(const bf16x8*)(buf + r*64 + ((q ^ (r & 3)) << 4));
}

// stage [128 rows][32 cols] bf16 (8KB) via global_load_lds; global pitch 1024B.
__device__ __forceinline__ void stageB32(const ushort* grow, char* lds, int tid){
  const char* gb = (const char*)grow;
  #pragma unroll
  for (int i = 0; i < 2; ++i){
    int lin = i*4096 + tid*16;
    int r = lin >> 6;
    int g = (lin >> 4) & 3;
    load_lds16(gb + r*1024 + ((g ^ (r & 3)) << 4), lds + i*4096 + ((tid >> 6) << 10));
  }
}

// pack 8 fp32 -> hi/lo bf16 pairs
__device__ __forceinline__ void pack8(const float* fv, uint* ph, uint* pl){
  #pragma unroll
  for (int q=0;q<4;++q){
    float f0 = fv[2*q], f1 = fv[2*q+1];
    ushort h0 = f2bf(f0), h1 = f2bf(f1);
    ushort s0 = f2bf(f0 - bf2f(h0)), s1 = f2bf(f1 - bf2f(h1));
    ph[q] = (uint)h0 | ((uint)h1 << 16);
    pl[q] = (uint)s0 | ((uint)s1 << 16);
  }
}
__device__ __forceinline__ void writeA2p(char* hbuf, char* lbuf, int ar, int acq,
                                         const uint* ph, const uint* pl){
  int off = ar*64 + ((acq ^ (ar & 3)) << 4);
  *(uint4*)(hbuf + off) = make_uint4(ph[0],ph[1],ph[2],ph[3]);
  *(uint4*)(lbuf + off) = make_uint4(pl[0],pl[1],pl[2],pl[3]);
}

// ---- kconv: We [E][D][O] f32 -> Wt [E][O][D] bf16 ; Wg1 [D][H] f32 -> W1h/W1l [H][D] bf16
__global__ void kconv(const float* __restrict__ We, const float* __restrict__ Wg1,
                      ushort* __restrict__ Wt, ushort* __restrict__ W1h, ushort* __restrict__ W1l){
  __shared__ float sh[64*65];
  int bx = blockIdx.x, tid = threadIdx.x;
  if (bx < 1024){
    int e = bx >> 6, dt = (bx >> 3) & 7, ot = bx & 7;
    const float* src = We + (size_t)e*262144 + (size_t)dt*64*512 + ot*64;
    #pragma unroll
    for (int it=0; it<16; ++it){ int idx = it*256+tid; int dl = idx>>6, ol = idx&63;
      sh[dl*65+ol] = src[dl*512+ol]; }
    __syncthreads();
    ushort* dst = Wt + (size_t)e*262144 + (size_t)ot*64*512 + dt*64;
    #pragma unroll
    for (int it=0; it<16; ++it){ int idx = it*256+tid; int ol = idx>>6, dl = idx&63;
      dst[(size_t)ol*512+dl] = f2bf(sh[dl*65+ol]); }
  } else {
    int q = bx - 1024;
    int dt = q >> 1, ht = q & 1;
    const float* src = Wg1 + (size_t)dt*64*128 + ht*64;
    #pragma unroll
    for (int it=0; it<16; ++it){ int idx = it*256+tid; int dl = idx>>6, ol = idx&63;
      sh[dl*65+ol] = src[dl*128+ol]; }
    __syncthreads();
    #pragma unroll
    for (int it=0; it<16; ++it){ int idx = it*256+tid; int ol = idx>>6, dl = idx&63;
      float wv = sh[dl*65+ol];
      ushort hi = f2bf(wv);
      ushort lo = f2bf(wv - bf2f(hi));
      size_t o = (size_t)(ht*64+ol)*512 + dt*64+dl;
      W1h[o] = hi; W1l[o] = lo; }
  }
}

// ---- kgate: fused gating + xbf16 producer + pair histogram.
__global__ __launch_bounds__(256) void kgate(
    const float* __restrict__ x, const ushort* __restrict__ W1h, const ushort* __restrict__ W1l,
    const float* __restrict__ bg1, const float* __restrict__ Wg2, const float* __restrict__ bg2,
    ushort* __restrict__ xbf,
    int2* __restrict__ gate_e, float2* __restrict__ gate_g,
    int* __restrict__ refine_cnt, int* __restrict__ refine_list, int* __restrict__ counts)
{
  __shared__ __align__(16) char sm[49152];
  const int BOFF = 16384;
  int tid = threadIdx.x, bid = blockIdx.x;
  int lane = tid & 63, w = tid >> 6, wm = w >> 1, wn = w & 1;
  int t0 = bid * 64;
  int ar = tid >> 2, acq = tid & 3;
  const float* xrow = x + (size_t)(t0 + ar) * DDIM;
  char* xbfb = (char*)xbf;
  f32x4 acc[2][4];
  #pragma unroll
  for (int n=0;n<4;++n){
    float bb = bg1[wn*64 + n*16 + (lane & 15)];
    f32x4 z = {bb, bb, bb, bb};
    acc[0][n] = z; acc[1][n] = z;
  }
  stageB32(W1h, sm + BOFF, tid);
  stageB32(W1l, sm + BOFF + 8192, tid);
  {
    float fv[8];
    *(float4*)&fv[0] = *(const float4*)(xrow + acq*8);
    *(float4*)&fv[4] = *(const float4*)(xrow + acq*8 + 4);
    uint ph[4], pl[4];
    pack8(fv, ph, pl);
    if (xbf) *(uint4*)(xbfb + (size_t)(t0+ar)*1024 + acq*16) = make_uint4(ph[0],ph[1],ph[2],ph[3]);
    writeA2p(sm, sm + 4096, ar, acq, ph, pl);
  }
  for (int ks = 0; ks < 16; ++ks){
    int b = ks & 1;
    asm volatile("s_waitcnt vmcnt(0)" ::: "memory");
    __syncthreads();
    uint ph[4], pl[4];
    if (ks < 15){
      int k2 = ks + 1, b2 = k2 & 1;
      stageB32(W1h + k2*32, sm + BOFF + b2*16384, tid);
      stageB32(W1l + k2*32, sm + BOFF + b2*16384 + 8192, tid);
      float fv[8];
      *(float4*)&fv[0] = *(const float4*)(xrow + k2*32 + acq*8);
      *(float4*)&fv[4] = *(const float4*)(xrow + k2*32 + acq*8 + 4);
      pack8(fv, ph, pl);
      if (xbf) *(uint4*)(xbfb + (size_t)(t0+ar)*1024 + k2*64 + acq*16) = make_uint4(ph[0],ph[1],ph[2],ph[3]);
    }
    const char* Ah = sm + b*8192;
    const char* Al = Ah + 4096;
    const char* Bh = sm + BOFF + b*16384;
    const char* Bl = Bh + 8192;
    bf16x8 ah[2], alv[2], bh[4], blv[4];
    #pragma unroll
    for (int m=0;m<2;++m){
      int r = wm*32 + m*16 + (lane & 15);
      ah[m]  = readF32c(Ah, r, lane >> 4);
      alv[m] = readF32c(Al, r, lane >> 4);
    }
    #pragma unroll
    for (int n=0;n<4;++n){
      int r = wn*64 + n*16 + (lane & 15);
      bh[n]  = readF32c(Bh, r, lane >> 4);
      blv[n] = readF32c(Bl, r, lane >> 4);
    }
    #pragma unroll
    for (int m=0;m<2;++m)
      #pragma unroll
      for (int n=0;n<4;++n){
        acc[m][n] = MFMA(ah[m],  bh[n],  acc[m][n]);
        acc[m][n] = MFMA(ah[m],  blv[n], acc[m][n]);
        acc[m][n] = MFMA(alv[m], bh[n],  acc[m][n]);
      }
    if (ks < 15){
      int b2 = (ks + 1) & 1;
      writeA2p(sm + b2*8192, sm + b2*8192 + 4096, ar, acq, ph, pl);
    }
  }
  __syncthreads();
  float* hl = (float*)sm;
  #pragma unroll
  for (int m=0;m<2;++m)
    #pragma unroll
    for (int n=0;n<4;++n)
      #pragma unroll
      for (int j=0;j<4;++j){
        int row = wm*32 + m*16 + ((lane >> 4) << 2) + j;
        int col = wn*64 + n*16 + (lane & 15);
        float uv = acc[m][n][j];
        hl[row*132 + col] = 0.5f * uv * (1.0f + erff(uv * 0.70710678118654752f));
      }
  __syncthreads();
  {
    int tt = tid >> 2, cc = tid & 3;
    float4 bb = *(const float4*)(bg2 + cc*4);
    float l0 = bb.x, l1 = bb.y, l2 = bb.z, l3 = bb.w;
    const float* hrow = hl + tt*132;
    #pragma unroll 8
    for (int i = 0; i < 128; ++i){
      float hv = hrow[i];
      float4 wv = *(const float4*)(Wg2 + i*16 + cc*4);
      l0 += hv*wv.x; l1 += hv*wv.y; l2 += hv*wv.z; l3 += hv*wv.w;
    }
    float* ll = (float*)(sm + 33792);
    *(float4*)(ll + tt*16 + cc*4) = make_float4(l0, l1, l2, l3);
  }
  int* hist = (int*)(sm + 40960);
  hist[tid] = 0;
  __syncthreads();
  if (tid < 64){
    int t = t0 + tid;
    const float* l = (const float*)(sm + 33792) + tid*16;
    float b1 = -1e30f, b2 = -1e30f, b3 = -1e30f; int e1 = 0, e2 = 0;
    #pragma unroll
    for (int e = 0; e < 16; ++e){
      float v = l[e];
      if (v > b1){ b3 = b2; b2 = b1; e2 = e1; b1 = v; e1 = e; }
      else if (v > b2){ b3 = b2; b2 = v; e2 = e; }
      else if (v > b3){ b3 = v; }
    }
    double s = 0.0;
    #pragma unroll
    for (int e = 0; e < 16; ++e) s += exp((double)l[e] - (double)b1);
    double inv = 1.0 / s;
    gate_e[t] = make_int2(e1, e2);
    gate_g[t] = make_float2((float)(inv + 1e-4), (float)(exp((double)b2 - (double)b1) * inv + 1e-4));
    if (b2 - b3 < 2e-4f){
      int pos = atomicAdd(refine_cnt, 1);
      refine_list[pos] = t;
    }
    int pa = min(e1, e2), pb = max(e1, e2);
    atomicAdd(&hist[pa*16 + pb], 1);
  }
  __syncthreads();
  if (hist[tid]) atomicAdd(&counts[tid], hist[tid]);
}

// ---- krefine: exact fp64 gating for flagged tokens; patches pair counts.
__global__ __launch_bounds__(128) void krefine(
    const float* __restrict__ x, const float* __restrict__ Wg1, const float* __restrict__ bg1,
    const float* __restrict__ Wg2, const float* __restrict__ bg2,
    const int* __restrict__ refine_cnt, const int* __restrict__ refine_list,
    int2* __restrict__ gate_e, float2* __restrict__ gate_g, int* __restrict__ counts)
{
  __shared__ float  xs[512];
  __shared__ double hd[128];
  __shared__ double ld[16];
  int tid = threadIdx.x;
  int rc = *refine_cnt;
  for (int i = blockIdx.x; i < rc; i += gridDim.x){
    __syncthreads();
    int t = refine_list[i];
    *(float4*)(xs + tid*4) = *(const float4*)(x + (size_t)t*DDIM + tid*4);
    __syncthreads();
    double a = (double)bg1[tid];
    for (int d = 0; d < 512; ++d) a += (double)xs[d] * (double)Wg1[d*128 + tid];
    hd[tid] = 0.5 * a * (1.0 + erf(a * 0.70710678118654752440));
    __syncthreads();
    if (tid < 16){
      double s = (double)bg2[tid];
      for (int k = 0; k < 128; ++k) s += hd[k] * (double)Wg2[k*16 + tid];
      ld[tid] = s;
    }
    __syncthreads();
    if (tid == 0){
      int2 olde = gate_e[t];
      double b1 = -1e300, b2 = -1e300; int e1 = 0, e2 = 0;
      for (int e = 0; e < 16; ++e){
        double v = ld[e];
        if (v > b1){ b2 = b1; e2 = e1; b1 = v; e1 = e; }
        else if (v > b2){ b2 = v; e2 = e; }
      }
      double s = 0.0;
      for (int e = 0; e < 16; ++e) s += exp(ld[e] - b1);
      double inv = 1.0 / s;
      int oldp = min(olde.x, olde.y)*16 + max(olde.x, olde.y);
      int newp = min(e1, e2)*16 + max(e1, e2);
      if (oldp != newp){ atomicSub(&counts[oldp], 1); atomicAdd(&counts[newp], 1); }
      gate_e[t] = make_int2(e1, e2);
      gate_g[t] = make_float2((float)(inv + 1e-4), (float)(exp(b2 - b1) * inv + 1e-4));
    }
  }
}

// ---- kscan: one wave. prefix over 256 pair counts + tile list (ts-row tiles).
__global__ void kscan(const int* __restrict__ counts, int* __restrict__ bases,
                      int* __restrict__ tile_pair, int* __restrict__ tile_row0, int* __restrict__ ntiles,
                      int ts){
  int l = threadIdx.x;
  int4 c = *(const int4*)(counts + l*4);
  int s = c.x + c.y + c.z + c.w;
  int ps = s;
  #pragma unroll
  for (int d = 1; d < 64; d <<= 1){ int v = __shfl_up(ps, d); if (l >= d) ps += v; }
  int ex = ps - s;
  bases[4*l+0] = ex;
  bases[4*l+1] = ex + c.x;
  bases[4*l+2] = ex + c.x + c.y;
  bases[4*l+3] = ex + c.x + c.y + c.z;
  if (l == 63) bases[256] = ex + s;
  int t0 = (c.x + ts-1) / ts, t1 = (c.y + ts-1) / ts, t2 = (c.z + ts-1) / ts, t3 = (c.w + ts-1) / ts;
  int tsum = t0 + t1 + t2 + t3;
  int pt = tsum;
  #pragma unroll
  for (int d = 1; d < 64; d <<= 1){ int v = __shfl_up(pt, d); if (l >= d) pt += v; }
  int ext = pt - tsum;
  if (l == 63) *ntiles = ext + tsum;
  int tb = ext;
  int cc[4] = {c.x, c.y, c.z, c.w};
  #pragma unroll
  for (int j = 0; j < 4; ++j){
    int pp = 4*l + j;
    for (int r = 0; r < cc[j]; r += ts){ tile_pair[tb] = pp; tile_row0[tb] = r; ++tb; }
  }
}

__global__ void kscatter(const int2* __restrict__ gate_e, const float2* __restrict__ gate_g,
                         const int* __restrict__ bases, int* __restrict__ cursors,
                         int* __restrict__ pair_tok, float2* __restrict__ pair_g){
  __shared__ int h[256];
  __shared__ int gb[256];
  int tid = threadIdx.x;
  h[tid] = 0; __syncthreads();
  int t = blockIdx.x*256 + tid;
  int2 ee = gate_e[t]; float2 gg = gate_g[t];
  int a, b; float ga, gbv;
  if (ee.x < ee.y){ a = ee.x; b = ee.y; ga = gg.x; gbv = gg.y; }
  else            { a = ee.y; b = ee.x; ga = gg.y; gbv = gg.x; }
  int p = a*16 + b;
  int off = atomicAdd(&h[p], 1);
  __syncthreads();
  if (h[tid]) gb[tid] = bases[tid] + atomicAdd(&cursors[tid], h[tid]);
  __syncthreads();
  int slot = gb[p] + off;
  pair_tok[slot] = t;
  pair_g[slot] = make_float2(ga, gbv);
}

// ======== kexpert2: 256x256 pair-bucket GEMM, 8-phase counted-vmcnt schedule ====
// 512 thr = 8 waves (2M x 4N); per-wave 128 rows x 64 cols; acc[8][4] f32x4.
// RAW s_barrier + un-clobbered s_waitcnt + sched_barrier(0) pins (m201 recipe):
// a "memory" clobber here makes the compiler drain vmcnt(0) per phase (T4 defeat).
#define SB0 __builtin_amdgcn_sched_barrier(0)
#define PH_MID do{ __builtin_amdgcn_s_barrier(); \
                   asm volatile("s_waitcnt lgkmcnt(0)"); SB0; }while(0)
#define PH_END do{ SB0; __builtin_amdgcn_s_barrier(); }while(0)

#define RDA(hp, mb) do{ \
  _Pragma("unroll") for (int m_=0;m_<4;++m_){ \
    int r_ = ((mb)+m_)*16 + l15; \
    af[m_][0] = readF64(hp, r_, l4); \
    af[m_][1] = readF64(hp, r_, 4+l4); }}while(0)
#define RDB(hp, bv, nb) do{ \
  _Pragma("unroll") for (int n_=0;n_<2;++n_){ \
    int r_ = bln + ((nb)+n_)*16 + l15; \
    bv[n_][0] = readF64(hp, r_, l4); \
    bv[n_][1] = readF64(hp, r_, 4+l4); }}while(0)
#define MMAC(bv, mb, nb) do{ \
  __builtin_amdgcn_s_setprio(1); \
  _Pragma("unroll") for (int m_=0;m_<4;++m_){ \
    _Pragma("unroll") for (int n_=0;n_<2;++n_){ \
      acc[(mb)+m_][(nb)+n_] = MFMA(af[m_][0], bv[n_][0], acc[(mb)+m_][(nb)+n_]); \
      acc[(mb)+m_][(nb)+n_] = MFMA(af[m_][1], bv[n_][1], acc[(mb)+m_][(nb)+n_]); }} \
  __builtin_amdgcn_s_setprio(0); \
}while(0)

__global__ __launch_bounds__(512, 2) void kexpert2(
    const ushort* __restrict__ xbf, const ushort* __restrict__ Wt, const float* __restrict__ be,
    float* __restrict__ out,
    const int* __restrict__ counts, const int* __restrict__ bases,
    const int* __restrict__ tile_pair, const int* __restrict__ tile_row0, const int* __restrict__ ntiles,
    const int* __restrict__ pair_tok, const float2* __restrict__ pair_g)
{
  __shared__ __align__(16) char sm[134144];
  const int BBASE = 65536, LTOK = 131072, LG = 132096;
  int bid = blockIdx.x;
  int tile = ((bid >> 4) << 3) | (bid & 7);   // col-block pair shares XCD
  int nt = (bid >> 3) & 1;
  if (tile >= *ntiles) return;
  int p = tile_pair[tile], row0 = tile_row0[tile];
  int base = bases[p], cnt = counts[p];
  int eA = p >> 4, eB = p & 15;
  int tid = threadIdx.x, lane = tid & 63, w = tid >> 6;
  int wm = w >> 2, wn = w & 3;
  int l15 = lane & 15, l4 = lane >> 4;
  int bln = (wn & 1) * 64;
  if (tid < 256){
    int rr = row0 + tid; bool v = rr < cnt;
    ((int*)(sm + LTOK))[tid] = v ? pair_tok[base + rr] : -1;
    ((float2*)(sm + LG))[tid] = v ? pair_g[base + rr] : make_float2(0.f, 1.f);
  }
  __syncthreads();

  int rr0 = tid >> 3;
  int sw = ((tid & 7) ^ (rr0 & 7)) << 4;
  const char* xb = (const char*)xbf;
  const char* srcA[2][2];
  #pragma unroll
  for (int h = 0; h < 2; ++h)
    #pragma unroll
    for (int i = 0; i < 2; ++i){
      int tk = ((const int*)(sm + LTOK))[h*128 + i*64 + rr0];
      if (tk < 0) tk = 0;
      srcA[h][i] = xb + (size_t)tk*1024 + sw;
    }
  const char* srcB0 = (const char*)Wt + (size_t)eA*524288 + (size_t)(nt*256 + rr0)*1024 + sw;
  long long edelt = ((long long)eB - eA) * 524288;
  char* dA = sm + w*1024;
  char* dB = sm + BBASE + w*1024;

  auto stA = [&](int t, int h){
    if (t >= NT) return;
    int ks = t & 7, bf_ = t & 1;
    load_lds16(srcA[h][0] + ks*128, dA + bf_*32768 + h*16384);
    load_lds16(srcA[h][1] + ks*128, dA + bf_*32768 + h*16384 + 8192);
  };
  auto stB = [&](int t, int h){
    if (t >= NT) return;
    int ks = t & 7, bf_ = t & 1;
    long long eo = ((t >= 8) ? edelt : 0) + ks*128;
    load_lds16(srcB0 + h*131072 + eo,         dB + bf_*32768 + h*16384);
    load_lds16(srcB0 + h*131072 + 65536 + eo, dB + bf_*32768 + h*16384 + 8192);
  };

  const char* A0 = sm + wm*16384;            // buf0 A, this wave's half
  const char* A1 = A0 + 32768;               // buf1
  const char* B0 = sm + BBASE + (wn >> 1)*16384;
  const char* B1 = B0 + 32768;

  f32x4 acc[8][4];
  #pragma unroll
  for (int m = 0; m < 8; ++m)
    #pragma unroll
    for (int n = 0; n < 4; ++n) acc[m][n] = (f32x4){0.f,0.f,0.f,0.f};

  // prologue: tile0 (A+B) + tile1 (B); tile1's A staged in ph1/2 of iter 0
  stA(0,0); stA(0,1); stB(0,0); stB(0,1); stB(1,0); stB(1,1);
  asm volatile("s_waitcnt vmcnt(4)"); SB0;
  __builtin_amdgcn_s_barrier();

  bf16x8 af[4][2], bL[2][2], bH[2][2];
  #pragma unroll 1
  for (int i = 0; i < 8; ++i){
    int t0 = 2*i, t1 = t0 + 1;
    // ph1: Q(m0-3, n0-1) of buf0
    RDA(A0, 0); RDB(B0, bL, 0); stA(t1, 0);
    PH_MID; MMAC(bL, 0, 0); PH_END;
    // ph2: Q(m0-3, n2-3)
    RDB(B0, bH, 2); stA(t1, 1);
    PH_MID; MMAC(bH, 0, 2); PH_END;
    // ph3: Q(m4-7, n2-3)
    RDA(A0, 4); stB(t0+2, 0);
    PH_MID; MMAC(bH, 4, 2); PH_END;
    // ph4: Q(m4-7, n0-1); sync point for buf1 consumption
    stB(t0+2, 1);
    if (i != 7) { asm volatile("s_waitcnt vmcnt(4)"); SB0; }
    else        { asm volatile("s_waitcnt vmcnt(0)"); SB0; }
    PH_MID; MMAC(bL, 4, 0); PH_END;
    // ph5: buf1 Q(m0-3, n0-1)
    RDA(A1, 0); RDB(B1, bL, 0); stA(t0+2, 0);
    PH_MID; MMAC(bL, 0, 0); PH_END;
    // ph6
    RDB(B1, bH, 2); stA(t0+2, 1);
    PH_MID; MMAC(bH, 0, 2); PH_END;
    // ph7
    RDA(A1, 4); stB(t1+2, 0);
    PH_MID; MMAC(bH, 4, 2); PH_END;
    // ph8; sync point for next-iter buf0 consumption
    stB(t1+2, 1);
    if (i != 7) { asm volatile("s_waitcnt vmcnt(4)"); SB0; }
    PH_MID; MMAC(bL, 4, 0); PH_END;
    if (i == 3){            // expert switch: fold gate-A into accumulator
      #pragma unroll
      for (int m = 0; m < 8; ++m)
        #pragma unroll
        for (int j = 0; j < 4; ++j){
          int row = wm*128 + m*16 + l4*4 + j;
          float2 g2 = ((const float2*)(sm + LG))[row];
          float r_ = g2.x / g2.y;
          #pragma unroll
          for (int n = 0; n < 4; ++n) acc[m][n][j] *= r_;
        }
    }
  }

  // epilogue: out = gB*acc + gA*bA + gB*bB
  float bcA[4], bcB[4];
  #pragma unroll
  for (int n = 0; n < 4; ++n){
    int col = nt*256 + wn*64 + n*16 + l15;
    bcA[n] = be[(size_t)eA*DDIM + col];
    bcB[n] = be[(size_t)eB*DDIM + col];
  }
  #pragma unroll
  for (int m = 0; m < 8; ++m)
    #pragma unroll
    for (int j = 0; j < 4; ++j){
      int row = wm*128 + m*16 + l4*4 + j;
      int tk = ((const int*)(sm + LTOK))[row];
      if (tk >= 0){
        float2 g2 = ((const float2*)(sm + LG))[row];
        float* orow = out + (size_t)tk*DDIM + nt*256 + wn*64;
        #pragma unroll
        for (int n = 0; n < 4; ++n)
          orow[n*16 + l15] = g2.y*acc[m][n][j] + g2.x*bcA[n] + g2.y*bcB[n];
      }
    }
}

// ---- kexpertF: fallback (no xbf room): 128x128 pair-bucket GEMM, fp32-A reg-staged.
__global__ __launch_bounds__(256, 2) void kexpertF(
    const float* __restrict__ x,
    const ushort* __restrict__ Wt, const float* __restrict__ be,
    float* __restrict__ out,
    const int* __restrict__ counts, const int* __restrict__ bases,
    const int* __restrict__ tile_pair, const int* __restrict__ tile_row0, const int* __restrict__ ntiles,
    const int* __restrict__ pair_tok, const float2* __restrict__ pair_g)
{
  __shared__ __align__(16) char sm[67072];
  const int ABUF = 0, BBUF = 32768, LTOK = 65536, LGOFF = 66048;
  int tile = blockIdx.x >> 2, nt = blockIdx.x & 3;
  if (tile >= *ntiles) return;
  int p = tile_pair[tile], row0 = tile_row0[tile];
  int base = bases[p], cnt = counts[p];
  int eA = p >> 4, eB = p & 15;
  int tid = threadIdx.x, lane = tid & 63;
  int w = tid >> 6, wm = w >> 1, wn = w & 1;
  if (tid < 128){
    int rr = row0 + tid; bool v = rr < cnt;
    ((int*)(sm + LTOK))[tid] = v ? pair_tok[base + rr] : -1;
    ((float2*)(sm + LGOFF))[tid] = v ? pair_g[base + rr] : make_float2(0.f, 0.f);
  }
  __syncthreads();
  const char* wb = (const char*)Wt;
  int grp = tid >> 3, gch = tid & 7;
  int swz = (gch ^ (grp & 7)) << 4;
  long long edelt = ((long long)eB - (long long)eA) * 524288;
  const char* srcB[4];
  #pragma unroll
  for (int i = 0; i < 4; ++i)
    srcB[i] = wb + (long long)eA*524288 + (size_t)(nt*128 + i*32 + grp)*1024 + swz;
  int arow = tid >> 1, ach = tid & 1;
  int tkr = ((const int*)(sm + LTOK))[arow];
  if (tkr < 0) tkr = 0;
  const float* xrow = x + (size_t)tkr*DDIM + ach*32;
  int ldst = (w << 10);
  #pragma unroll
  for (int i = 0; i < 4; ++i) load_lds16(srcB[i], sm + BBUF + i*4096 + ldst);
  {
    uint pk[16];
    #pragma unroll
    for (int q2 = 0; q2 < 4; ++q2){
      float4 fv = *(const float4*)(xrow + q2*8);
      float4 fw = *(const float4*)(xrow + q2*8 + 4);
      pk[q2*4+0] = (uint)f2bf(fv.x) | ((uint)f2bf(fv.y) << 16);
      pk[q2*4+1] = (uint)f2bf(fv.z) | ((uint)f2bf(fv.w) << 16);
      pk[q2*4+2] = (uint)f2bf(fw.x) | ((uint)f2bf(fw.y) << 16);
      pk[q2*4+3] = (uint)f2bf(fw.z) | ((uint)f2bf(fw.w) << 16);
    }
    #pragma unroll
    for (int q2 = 0; q2 < 4; ++q2){
      int g = ach*4 + q2;
      *(uint4*)(sm + ABUF + arow*128 + ((g ^ (arow & 7)) << 4)) =
          make_uint4(pk[q2*4], pk[q2*4+1], pk[q2*4+2], pk[q2*4+3]);
    }
  }
  f32x4 acc[4][4], res[4][4];
  #pragma unroll
  for (int m=0;m<4;++m)
    #pragma unroll
    for (int n=0;n<4;++n) acc[m][n] = (f32x4){0.f,0.f,0.f,0.f};
  for (int u = 0; u < 16; ++u){
    int b = u & 1;
    asm volatile("s_waitcnt vmcnt(0)" ::: "memory");
    __syncthreads();
    int un = u + 1;
    uint pk[16];
    if (un < 16){
      int b2 = un & 1;
      long long aoff = (long long)(un & 7) * 128;
      long long boff = aoff + ((un >> 3) ? edelt : 0);
      #pragma unroll
      for (int i = 0; i < 4; ++i)
        load_lds16(srcB[i] + boff, sm + BBUF + b2*16384 + i*4096 + ldst);
      const float* xr = xrow + (un & 7)*64;
      #pragma unroll
      for (int q2 = 0; q2 < 4; ++q2){
        float4 fv = *(const float4*)(xr + q2*8);
        float4 fw = *(const float4*)(xr + q2*8 + 4);
        pk[q2*4+0] = (uint)f2bf(fv.x) | ((uint)f2bf(fv.y) << 16);
        pk[q2*4+1] = (uint)f2bf(fv.z) | ((uint)f2bf(fv.w) << 16);
        pk[q2*4+2] = (uint)f2bf(fw.x) | ((uint)f2bf(fw.y) << 16);
        pk[q2*4+3] = (uint)f2bf(fw.z) | ((uint)f2bf(fw.w) << 16);
      }
    }
    const char* Ab = sm + ABUF + b*16384;
    const char* Bb = sm + BBUF + b*16384;
    bf16x8 af2[4][2], bf2[4][2];
    #pragma unroll
    for (int m=0;m<4;++m){
      int r = wm*64 + m*16 + (lane & 15);
      af2[m][0] = readF64(Ab, r, (lane >> 4));
      af2[m][1] = readF64(Ab, r, 4 + (lane >> 4));
    }
    #pragma unroll
    for (int n=0;n<4;++n){
      int r = wn*64 + n*16 + (lane & 15);
      bf2[n][0] = readF64(Bb, r, (lane >> 4));
      bf2[n][1] = readF64(Bb, r, 4 + (lane >> 4));
    }
    #pragma unroll
    for (int m=0;m<4;++m)
      #pragma unroll
      for (int n=0;n<4;++n){
        acc[m][n] = MFMA(af2[m][0], bf2[n][0], acc[m][n]);
        acc[m][n] = MFMA(af2[m][1], bf2[n][1], acc[m][n]);
      }
    if (un < 16){
      int b2 = un & 1;
      #pragma unroll
      for (int q2 = 0; q2 < 4; ++q2){
        int g = ach*4 + q2;
        *(uint4*)(sm + ABUF + b2*16384 + arow*128 + ((g ^ (arow & 7)) << 4)) =
            make_uint4(pk[q2*4], pk[q2*4+1], pk[q2*4+2], pk[q2*4+3]);
      }
    }
    if (u == 7){
      const float* bev = be + (size_t)eA*DDIM + nt*128;
      float bcol[4];
      #pragma unroll
      for (int n=0;n<4;++n) bcol[n] = bev[wn*64 + n*16 + (lane & 15)];
      #pragma unroll
      for (int m=0;m<4;++m)
        #pragma unroll
        for (int j=0;j<4;++j){
          int row = wm*64 + m*16 + ((lane >> 4) << 2) + j;
          float g = ((const float2*)(sm + LGOFF))[row].x;
          #pragma unroll
          for (int n=0;n<4;++n){
            res[m][n][j] = g * (acc[m][n][j] + bcol[n]);
            acc[m][n][j] = 0.f;
          }
        }
    }
    if (u == 15){
      const float* bev = be + (size_t)eB*DDIM + nt*128;
      float bcol[4];
      #pragma unroll
      for (int n=0;n<4;++n) bcol[n] = bev[wn*64 + n*16 + (lane & 15)];
      #pragma unroll
      for (int m=0;m<4;++m)
        #pragma unroll
        for (int j=0;j<4;++j){
          int row = wm*64 + m*16 + ((lane >> 4) << 2) + j;
          int tk = ((const int*)(sm + LTOK))[row];
          float g = ((const float2*)(sm + LGOFF))[row].y;
          if (tk >= 0){
            float* orow = out + (size_t)tk*DDIM + nt*128;
            #pragma unroll
            for (int n=0;n<4;++n)
              orow[wn*64 + n*16 + (lane & 15)] = res[m][n][j] + g * (acc[m][n][j] + bcol[n]);
          }
        }
    }
  }
}

// ---- host launch --------------------------------------------------------------
extern "C" void kernel_launch(void* const* d_in, const int* in_sizes, int n_in,
                              void* d_out, int out_size, void* d_ws, size_t ws_size,
                              hipStream_t stream)
{
  const float* x   = (const float*)d_in[0];
  const float* Wg1 = (const float*)d_in[1];
  const float* bg1 = (const float*)d_in[2];
  const float* Wg2 = (const float*)d_in[3];
  const float* bg2 = (const float*)d_in[4];
  const float* We  = (const float*)d_in[5];
  const float* be  = (const float*)d_in[6];
  float* out = (float*)d_out;
  char* ws = (char*)d_ws;

  ushort* Wt        = (ushort*)(ws + 0);          // 8,388,608
  ushort* W1h       = (ushort*)(ws + 8388608);    //   131,072
  ushort* W1l       = (ushort*)(ws + 8519680);    //   131,072
  char*   CTRL      = ws + 8650752;               //     8,192
  int*  refine_cnt  = (int*)(CTRL);
  int*  ntiles      = (int*)(CTRL + 4);
  int*  counts      = (int*)(CTRL + 64);          // 256 ints
  int*  cursors     = (int*)(CTRL + 2048);        // 256 ints
  int*  bases       = (int*)(CTRL + 4096);        // 257 ints
  int2*   gate_e    = (int2*)(ws + 8658944);      // 1,048,576
  float2* gate_g    = (float2*)(ws + 9707520);    // 1,048,576
  int*  refine_list = (int*)(ws + 10756096);      //   524,288
  int*  pair_tok    = (int*)(ws + 11280384);      //   524,288
  float2* pair_g    = (float2*)(ws + 11804672);   // 1,048,576
  int*  tile_pair   = (int*)(ws + 12853248);      //    10,240
  int*  tile_row0   = (int*)(ws + 12863488);      //    10,240
  const size_t XBF_OFF = 16777216ull;
  const size_t XBF_BYTES = (size_t)NTOK * DDIM * 2;   // 134 MB
  bool bf16a = ws_size >= XBF_OFF + XBF_BYTES;
  ushort* xbf = bf16a ? (ushort*)(ws + XBF_OFF) : nullptr;

  hipMemsetAsync(CTRL, 0, 8192, stream);
  hipLaunchKernelGGL(kconv,    dim3(1040), dim3(256), 0, stream, We, Wg1, Wt, W1h, W1l);
  hipLaunchKernelGGL(kgate,    dim3(2048), dim3(256), 0, stream, x, W1h, W1l, bg1, Wg2, bg2,
                     xbf, gate_e, gate_g, refine_cnt, refine_list, counts);
  hipLaunchKernelGGL(krefine,  dim3(512),  dim3(128), 0, stream, x, Wg1, bg1, Wg2, bg2,
                     refine_cnt, refine_list, gate_e, gate_g, counts);
  hipLaunchKernelGGL(kscan,    dim3(1),    dim3(64),  0, stream, counts, bases, tile_pair, tile_row0, ntiles,
                     bf16a ? 256 : 128);
  hipLaunchKernelGGL(kscatter, dim3(512),  dim3(256), 0, stream, gate_e, gate_g, bases, cursors, pair_tok, pair_g);
  if (bf16a)
    hipLaunchKernelGGL(kexpert2, dim3(1408), dim3(512), 0, stream, xbf, Wt, be, out,
                       counts, bases, tile_pair, tile_row0, ntiles, pair_tok, pair_g);
  else
    hipLaunchKernelGGL(kexpertF, dim3(5120), dim3(256), 0, stream, x, Wt, be, out,
                       counts, bases, tile_pair, tile_row0, ntiles, pair_tok, pair_g);
  (void)in_sizes; (void)n_in; (void)out_size; (void)ws_size;
}